// Round 3
// baseline (708.533 us; speedup 1.0000x reference)
//
#include <hip/hip_runtime.h>

// IJGNN attention-MPNN, 3 iterations. fp32 in/out, bf16 internal.
// Edges processed in dst-sorted (CSR) order; edge head scatters back via eid.
// This rev: edge_fused with (a) full A-tile register preload (all HBM loads
// issued upfront), (b) B fragments read directly from L2-hot WeT (no B LDS
// staging), (c) double-buffered A chunk -> 1 barrier per K-chunk, (d) kc0 as
// template param (static register indexing). aggregate: 8 edges/iteration.

#define GN 25000
#define GE 400000
#define NODE_BLKS 196    // ceil(GN/128)
#define EDGE_BLKS 6250   // GE/64 exact (edge_fused tiles)
#define HEAD_EBLKS 3125  // GE/128 exact (head_kernel tiles)

typedef unsigned short u16;
typedef __attribute__((ext_vector_type(8))) short bf16x8;
typedef __attribute__((ext_vector_type(4))) float f32x4;

__device__ inline float b2f(u16 v) {
  union { unsigned int u; float f; } x; x.u = ((unsigned int)v) << 16; return x.f;
}
__device__ inline u16 f2b(float f) {
  union { float f; unsigned int u; } x; x.f = f;
  unsigned int u = x.u;
  u += 0x7fffu + ((u >> 16) & 1u);
  return (u16)(u >> 16);
}

// ---------------- dtype probe + convert ----------------
__global__ void detect_dtype(const void* nf, int* flag) {
  if (blockIdx.x == 0 && threadIdx.x == 0) {
    const u16* p = (const u16*)nf;
    int cnt = 0;
    for (int i = 0; i < 512; i += 2) {
      int e = (p[i] >> 7) & 0xFF;
      if (e >= 0x70 && e <= 0x85) cnt++;
    }
    *flag = (cnt < 128) ? 1 : 0;
  }
}

__global__ void convert_kernel(const void* src, u16* dst, long n, const int* flag) {
  int f32 = *flag;
  long i = (long)blockIdx.x * blockDim.x + threadIdx.x;
  long stride = (long)gridDim.x * blockDim.x;
  for (; i < n; i += stride)
    dst[i] = f32 ? f2b(((const float*)src)[i]) : ((const u16*)src)[i];
}

// gather ef rows into dst-sorted order (+convert)
__global__ void gather_ef(const void* ef, const int* eid, u16* efc, const int* flag) {
  int f32 = *flag;
  long idx = (long)blockIdx.x * blockDim.x + threadIdx.x;
  long stride = (long)gridDim.x * blockDim.x;
  long ntot = (long)GE * 32;
  for (; idx < ntot; idx += stride) {
    long j = idx >> 5;
    int c = (int)(idx & 31);
    long e = eid[j];
    efc[idx] = f32 ? f2b(((const float*)ef)[e * 32 + c]) : ((const u16*)ef)[e * 32 + c];
  }
}

// ---------------- weight prep: convert (raw f32/bf16) + transpose, one launch ----------------
__global__ void prep_weights(const void* We, const void* Wn, const void* Wa,
                             const void* Won, const void* Woe,
                             const void* be, const void* ba, const void* bn,
                             const void* bno, const void* beo,
                             u16* WeT, u16* WnpT, u16* WnuT, u16* WoN, u16* WoE,
                             u16* Wac, u16* bec, u16* bac, u16* bnc, u16* bnoc, u16* beoc,
                             const int* flag) {
  int f32 = *flag;
  auto ld = [&](const void* p, long i) -> u16 {
    return f32 ? f2b(((const float*)p)[i]) : ((const u16*)p)[i];
  };
  int tid = blockIdx.x * blockDim.x + threadIdx.x;
  int nt = gridDim.x * blockDim.x;
  for (int i = tid; i < 128 * 160; i += nt) { int n = i / 160, k = i % 160; WeT[i] = ld(We, (long)(320 + k) * 128 + n); }
  for (int i = tid; i < 256 * 160; i += nt) {
    int c = i / 160, k = i % 160;
    WnpT[i] = (c < 128) ? ld(We, (long)k * 128 + c) : ld(We, (long)(160 + k) * 128 + (c - 128));
  }
  for (int i = tid; i < 128 * 288; i += nt) { int c = i / 288, k = i % 288; WnuT[i] = ld(Wn, (long)k * 128 + c); }
  for (int i = tid; i < 32 * 128; i += nt) {
    int c = i / 128, k = i % 128;
    WoN[i] = ld(Won, (long)k * 32 + c);
    WoE[i] = ld(Woe, (long)k * 32 + c);
  }
  for (int i = tid; i < 480; i += nt) Wac[i] = ld(Wa, i);
  for (int i = tid; i < 128; i += nt) { bec[i] = ld(be, i); bnc[i] = ld(bn, i); }
  for (int i = tid; i < 32; i += nt) { bnoc[i] = ld(bno, i); beoc[i] = ld(beo, i); }
  if (tid == 0) bac[0] = ld(ba, 0);
}

// ---------------- CSR build ----------------
__global__ void hist_kernel(const int* dst, int* counts, int n) {
  for (int e = blockIdx.x * blockDim.x + threadIdx.x; e < n; e += gridDim.x * blockDim.x)
    atomicAdd(&counts[dst[e]], 1);
}

__global__ __launch_bounds__(256) void scan_kernel(int* cursor, int* rowptr, int n) {
  __shared__ int part[256];
  int t = threadIdx.x;
  int per = (n + 255) / 256;
  int lo = t * per;
  int hi = lo + per; if (hi > n) hi = n;
  if (lo > n) lo = n;
  int s = 0;
  for (int i = lo; i < hi; ++i) s += cursor[i];
  part[t] = s;
  __syncthreads();
  for (int off = 1; off < 256; off <<= 1) {
    int v = (t >= off) ? part[t - off] : 0;
    __syncthreads();
    part[t] += v;
    __syncthreads();
  }
  int run = (t > 0) ? part[t - 1] : 0;
  for (int i = lo; i < hi; ++i) {
    int c = cursor[i];
    cursor[i] = run;
    rowptr[i + 1] = run + c;
    run += c;
  }
  if (t == 0) rowptr[0] = 0;
}

// fill CSR order + gather src/dst meta in the same pass
__global__ void fill_kernel(const int* src, const int* dst, int* cursor, int* eid,
                            int* srcs, int* dsts, int n) {
  for (int e = blockIdx.x * blockDim.x + threadIdx.x; e < n; e += gridDim.x * blockDim.x) {
    int d = dst[e];
    int p = atomicAdd(&cursor[d], 1);
    eid[p] = e;
    srcs[p] = src[e];
    dsts[p] = d;
  }
}

// ---------------- node projections (MFMA): Xs/Xd [N,128] bf16, as/ad [N] fp32 ----------------
__global__ __launch_bounds__(256)
void node_proj(const u16* HNF, const u16* nf, const u16* WnpT, const u16* W_attn,
               u16* Xs, u16* Xd, float* as_, float* ad_, int kc0, int nrows) {
  __shared__ union {
    struct { __align__(16) u16 A[128][40]; __align__(16) u16 B[128][40]; } st;
    u16 C[128][130];  // bf16 transpose buffer (final values; no extra rounding)
  } sm;
  __shared__ float dotbuf[128][2];
  int sel = blockIdx.y, blk = blockIdx.x, tid = threadIdx.x;
  int lane = tid & 63, wv = tid >> 6, wr = wv & 1, wc = wv >> 1;
  const u16* BT = WnpT + sel * 128 * 160;
  u16* OUT = sel ? Xd : Xs;
  float* AOUT = sel ? ad_ : as_;
  const u16* wa = W_attn + sel * 160;
  f32x4 acc[4][4];
  f32x4 zf = {0.f, 0.f, 0.f, 0.f};
  for (int i = 0; i < 4; ++i) for (int j = 0; j < 4; ++j) acc[i][j] = zf;
  float dp = 0.f;
  int arow = tid >> 1, ahalf = (tid & 1) * 16;
  int r0 = blk * 128;
  for (int kc = kc0; kc < 5; ++kc) {
    {
      int r = r0 + arow;
      uint4 v0 = make_uint4(0, 0, 0, 0), v1 = make_uint4(0, 0, 0, 0);
      if (r < nrows) {
        const uint4* p = (kc < 4) ? (const uint4*)(HNF + (size_t)r * 128 + kc * 32 + ahalf)
                                  : (const uint4*)(nf + (size_t)r * 32 + ahalf);
        v0 = p[0]; v1 = p[1];
      }
      *(uint4*)&sm.st.A[arow][ahalf] = v0;
      *(uint4*)&sm.st.A[arow][ahalf + 8] = v1;
    }
    {
      const uint4* p = (const uint4*)(BT + arow * 160 + kc * 32 + ahalf);
      uint4 v0 = p[0], v1 = p[1];
      *(uint4*)&sm.st.B[arow][ahalf] = v0;
      *(uint4*)&sm.st.B[arow][ahalf + 8] = v1;
    }
    __syncthreads();
    {
      float s = 0.f;
      for (int j = 0; j < 16; ++j) s += b2f(sm.st.A[arow][ahalf + j]) * b2f(wa[kc * 32 + ahalf + j]);
      dp += s;
    }
    int q = lane >> 4, l16 = lane & 15;
    bf16x8 af[4], bfr[4];
    for (int i = 0; i < 4; ++i) af[i] = *(const bf16x8*)&sm.st.A[wr * 64 + i * 16 + l16][q * 8];
    for (int j = 0; j < 4; ++j) bfr[j] = *(const bf16x8*)&sm.st.B[wc * 64 + j * 16 + l16][q * 8];
    for (int i = 0; i < 4; ++i)
      for (int j = 0; j < 4; ++j)
        acc[i][j] = __builtin_amdgcn_mfma_f32_16x16x32_bf16(af[i], bfr[j], acc[i][j], 0, 0, 0);
    __syncthreads();
  }
  dotbuf[arow][tid & 1] = dp;
  // scatter acc -> LDS transpose buffer (overlays staging; K-loop is done)
  {
    int q = lane >> 4, l16 = lane & 15;
    for (int i = 0; i < 4; ++i)
      for (int j = 0; j < 4; ++j) {
        int col = wc * 64 + j * 16 + l16;
        for (int rr = 0; rr < 4; ++rr) {
          int row = wr * 64 + i * 16 + q * 4 + rr;
          sm.C[row][col] = f2b(acc[i][j][rr]);
        }
      }
  }
  __syncthreads();
  if (tid < 128) {
    int r = r0 + tid;
    if (r < nrows) AOUT[r] = dotbuf[tid][0] + dotbuf[tid][1];
  }
  // vectorized store: each thread owns one row-half (64 cols = 8x dwordx4)
  {
    int r = tid >> 1, h = (tid & 1) * 64;
    int rg = r0 + r;
    if (rg < nrows) {
      uint4* po = (uint4*)(OUT + (size_t)rg * 128 + h);
      for (int k = 0; k < 8; ++k) {
        unsigned int a0 = *(const unsigned int*)&sm.C[r][h + k * 8];
        unsigned int a1 = *(const unsigned int*)&sm.C[r][h + k * 8 + 2];
        unsigned int a2 = *(const unsigned int*)&sm.C[r][h + k * 8 + 4];
        unsigned int a3 = *(const unsigned int*)&sm.C[r][h + k * 8 + 6];
        po[k] = make_uint4(a0, a1, a2, a3);
      }
    }
  }
}

// ---------------- edge stage: 64-edge tiles, full A reg-preload, B frags from L2 ----------------
// A tile (64 edges x 160 K) preloaded to registers (5 x dwordx4/thread) -- all
// HBM loads issued at block start. B fragments loaded per-lane straight from
// L2-hot WeT (40KB constant), 1 chunk ahead. A chunk double-buffered in LDS ->
// exactly 1 barrier per K-chunk. Epilogue: two 64-col passes through f32 LDS
// transpose (no extra rounding), vector gathers of Xs/Xd + vector HEF stores.
template <int KC0>
__global__ __launch_bounds__(256, 4)
void edge_fused(u16* HEF, const u16* ef, const u16* WeT, const u16* W_attn,
                const u16* b_edge, const u16* b_attn, const int* srcs, const int* dsts,
                const u16* Xs, const u16* Xd, const float* as_, const float* ad_,
                float* logit) {
  __shared__ union {
    __align__(16) u16 A[2][64][40];  // double-buffered A chunk (10.2KB)
    float C[64][65];                 // epilogue transpose (16.6KB); bank spread
  } sm;
  __shared__ float dotbuf[64];
  int blk = blockIdx.x, tid = threadIdx.x;
  int lane = tid & 63, wv = tid >> 6, wr = wv & 1, wc = wv >> 1;
  int q = lane >> 4, l16 = lane & 15;
  f32x4 acc[2][4];
  f32x4 zf = {0.f, 0.f, 0.f, 0.f};
  for (int i = 0; i < 2; ++i) for (int j = 0; j < 4; ++j) acc[i][j] = zf;
  float dp[2] = {0.f, 0.f};
  long e0 = (long)blk * 64;
  long ea = e0 + (tid >> 2);
  int qp = (tid & 3) * 8;  // A col offset (u16 units), 16B per thread
  const u16* wa = W_attn + 320;

  // preload ALL A chunks (HBM stream) -- issued back-to-back, no in-loop waits
  uint4 va[5];
#pragma unroll
  for (int kc = KC0; kc < 5; ++kc)
    va[kc] = (kc < 4) ? *(const uint4*)(HEF + ea * 128 + kc * 32 + qp)
                      : *(const uint4*)(ef + ea * 32 + qp);
  // B fragments straight from global (L2-hot); bf[kc] live only around its MFMA
  bf16x8 bf[5][4];
#pragma unroll
  for (int j = 0; j < 4; ++j)
    bf[KC0][j] = *(const bf16x8*)(WeT + (size_t)(wc * 64 + j * 16 + l16) * 160 + KC0 * 32 + q * 8);

#pragma unroll
  for (int kc = KC0; kc < 5; ++kc) {
    int buf = kc & 1;
    *(uint4*)&sm.A[buf][tid >> 2][qp] = va[kc];
    if (kc < 4) {
#pragma unroll
      for (int j = 0; j < 4; ++j)
        bf[kc + 1][j] = *(const bf16x8*)(WeT + (size_t)(wc * 64 + j * 16 + l16) * 160 + (kc + 1) * 32 + q * 8);
    }
    __syncthreads();
    bf16x8 af[2];
    for (int i = 0; i < 2; ++i) af[i] = *(const bf16x8*)&sm.A[buf][wr * 32 + i * 16 + l16][q * 8];
    if (wc == 0) {
      bf16x8 wv8 = *(const bf16x8*)&wa[kc * 32 + q * 8];
      float wf[8];
      for (int j = 0; j < 8; ++j) wf[j] = b2f((u16)wv8[j]);
      for (int i = 0; i < 2; ++i)
        for (int j = 0; j < 8; ++j) dp[i] += b2f((u16)af[i][j]) * wf[j];
    }
    for (int i = 0; i < 2; ++i)
      for (int j = 0; j < 4; ++j)
        acc[i][j] = __builtin_amdgcn_mfma_f32_16x16x32_bf16(af[i], bf[kc][j], acc[i][j], 0, 0, 0);
  }
  if (wc == 0) {
    for (int i = 0; i < 2; ++i) {
      dp[i] += __shfl_xor(dp[i], 16);
      dp[i] += __shfl_xor(dp[i], 32);
    }
    if (q == 0)
      for (int i = 0; i < 2; ++i) dotbuf[wr * 32 + i * 16 + l16] = dp[i];
  }
  int r = tid >> 2, qh = tid & 3;  // each thread: one edge row, 16 cols/pass
  long e = e0 + r;
  int s = srcs[e], d = dsts[e];
#pragma unroll
  for (int p = 0; p < 2; ++p) {
    int cb = p * 64 + qh * 16;
    // issue vector gathers early: latency hides under barrier + LDS scatter
    const uint4* ps = (const uint4*)(Xs + (size_t)s * 128 + cb);
    const uint4* pd = (const uint4*)(Xd + (size_t)d * 128 + cb);
    uint4 gs0 = ps[0], gs1 = ps[1], gd0 = pd[0], gd1 = pd[1];
    // p=0: wait for all waves' last A-reads + dotbuf writes before overlaying C
    // p=1: wait for pass-0 C reads before rewriting C
    __syncthreads();
    if (wc == p) {  // this wave pair's acc covers cols [p*64, p*64+64)
      for (int i = 0; i < 2; ++i)
        for (int j = 0; j < 4; ++j) {
          int col = j * 16 + l16;
          float bb = b2f(b_edge[p * 64 + col]);
          for (int rr = 0; rr < 4; ++rr)
            sm.C[wr * 32 + i * 16 + q * 4 + rr][col] = acc[i][j][rr] + bb;
        }
    }
    __syncthreads();
    if (p == 0 && tid < 64) {
      long ee = e0 + tid;
      logit[ee] = dotbuf[tid] + as_[srcs[ee]] + ad_[dsts[ee]] + b2f(b_attn[0]);
    }
    unsigned int us[8], ud[8];
    *(uint4*)&us[0] = gs0; *(uint4*)&us[4] = gs1;
    *(uint4*)&ud[0] = gd0; *(uint4*)&ud[4] = gd1;
    unsigned int ov[8];
    for (int w = 0; w < 8; ++w) {
      float c0 = sm.C[r][qh * 16 + 2 * w];
      float c1 = sm.C[r][qh * 16 + 2 * w + 1];
      float v0 = c0 + b2f((u16)(us[w] & 0xffffu)) + b2f((u16)(ud[w] & 0xffffu));
      float v1 = c1 + b2f((u16)(us[w] >> 16)) + b2f((u16)(ud[w] >> 16));
      ov[w] = (unsigned int)f2b(fmaxf(v0, 0.f)) | ((unsigned int)f2b(fmaxf(v1, 0.f)) << 16);
    }
    uint4* po = (uint4*)(HEF + e * 128 + cb);
    po[0] = *(uint4*)&ov[0];
    po[1] = *(uint4*)&ov[4];
  }
}

// ---------------- per-dst softmax + aggregation ----------------
// 1 wave per dst row; 8 edges/iteration: lane = (edge-slot sub, col-group cl),
// 32B/lane M reads, 3-level shfl_xor fold over the 8 edge-slots.
__global__ __launch_bounds__(256)
void aggregate(const int* rowptr, const float* logit, const u16* M, u16* AGG, int nrows) {
  int gw = (blockIdx.x * blockDim.x + threadIdx.x) >> 6;
  int lane = threadIdx.x & 63;
  if (gw >= nrows) return;
  int beg = rowptr[gw], end = rowptr[gw + 1];
  int sub = lane >> 3, cl = lane & 7;
  float mx = -1e30f;
  for (int j = beg + lane; j < end; j += 64) mx = fmaxf(mx, logit[j]);
  for (int off = 32; off > 0; off >>= 1) mx = fmaxf(mx, __shfl_xor(mx, off));
  float acc[16];
  for (int t = 0; t < 16; ++t) acc[t] = 0.f;
  float denom = 0.f;
  for (int j0 = beg; j0 < end; j0 += 8) {
    int j = j0 + sub;
    float w = 0.f;
    uint4 m0 = make_uint4(0, 0, 0, 0), m1 = make_uint4(0, 0, 0, 0);
    if (j < end) {
      w = __expf(logit[j] - mx);
      const uint4* mp = (const uint4*)(M + (size_t)j * 128 + cl * 16);
      m0 = mp[0]; m1 = mp[1];
    }
    denom += w;
    const unsigned int* mw0 = (const unsigned int*)&m0;
    const unsigned int* mw1 = (const unsigned int*)&m1;
    for (int t = 0; t < 4; ++t) {
      acc[2 * t]     += w * b2f((u16)(mw0[t] & 0xffffu));
      acc[2 * t + 1] += w * b2f((u16)(mw0[t] >> 16));
      acc[8 + 2 * t]     += w * b2f((u16)(mw1[t] & 0xffffu));
      acc[8 + 2 * t + 1] += w * b2f((u16)(mw1[t] >> 16));
    }
  }
  denom += __shfl_xor(denom, 8);
  denom += __shfl_xor(denom, 16);
  denom += __shfl_xor(denom, 32);
  for (int t = 0; t < 16; ++t) {
    acc[t] += __shfl_xor(acc[t], 8);
    acc[t] += __shfl_xor(acc[t], 16);
    acc[t] += __shfl_xor(acc[t], 32);
  }
  float inv = 1.0f / fmaxf(denom, 1e-16f);
  if (sub == 0) {
    unsigned int ov[8];
    for (int t = 0; t < 8; ++t)
      ov[t] = (unsigned int)f2b(acc[2 * t] * inv) | ((unsigned int)f2b(acc[2 * t + 1] * inv) << 16);
    uint4* po = (uint4*)(AGG + (size_t)gw * 128 + cl * 16);
    po[0] = *(uint4*)&ov[0];
    po[1] = *(uint4*)&ov[4];
  }
}

// ---------------- node update (MFMA, in-place HNF) ----------------
__global__ __launch_bounds__(256)
void node_update(u16* HNF, const u16* nf, const u16* AGG, const u16* WnuT,
                 const u16* b_node, int kc0, int nrows) {
  __shared__ union {
    struct { __align__(16) u16 A[128][40]; __align__(16) u16 B[128][40]; } st;
    u16 C[128][130];
  } sm;
  int blk = blockIdx.x, tid = threadIdx.x;
  int lane = tid & 63, wv = tid >> 6, wr = wv & 1, wc = wv >> 1;
  f32x4 acc[4][4];
  f32x4 zf = {0.f, 0.f, 0.f, 0.f};
  for (int i = 0; i < 4; ++i) for (int j = 0; j < 4; ++j) acc[i][j] = zf;
  int arow = tid >> 1, ahalf = (tid & 1) * 16;
  int r0 = blk * 128;
  for (int kc = kc0; kc < 9; ++kc) {
    {
      int r = r0 + arow;
      uint4 v0 = make_uint4(0, 0, 0, 0), v1 = make_uint4(0, 0, 0, 0);
      if (r < nrows) {
        const u16* p;
        if (kc < 4) p = HNF + (size_t)r * 128 + kc * 32 + ahalf;
        else if (kc == 4) p = nf + (size_t)r * 32 + ahalf;
        else p = AGG + (size_t)r * 128 + (kc - 5) * 32 + ahalf;
        v0 = ((const uint4*)p)[0];
        v1 = ((const uint4*)p)[1];
      }
      *(uint4*)&sm.st.A[arow][ahalf] = v0;
      *(uint4*)&sm.st.A[arow][ahalf + 8] = v1;
    }
    {
      const uint4* p = (const uint4*)(WnuT + arow * 288 + kc * 32 + ahalf);
      uint4 v0 = p[0], v1 = p[1];
      *(uint4*)&sm.st.B[arow][ahalf] = v0;
      *(uint4*)&sm.st.B[arow][ahalf + 8] = v1;
    }
    __syncthreads();
    int q = lane >> 4, l16 = lane & 15;
    bf16x8 af[4], bfr[4];
    for (int i = 0; i < 4; ++i) af[i] = *(const bf16x8*)&sm.st.A[wr * 64 + i * 16 + l16][q * 8];
    for (int j = 0; j < 4; ++j) bfr[j] = *(const bf16x8*)&sm.st.B[wc * 64 + j * 16 + l16][q * 8];
    for (int i = 0; i < 4; ++i)
      for (int j = 0; j < 4; ++j)
        acc[i][j] = __builtin_amdgcn_mfma_f32_16x16x32_bf16(af[i], bfr[j], acc[i][j], 0, 0, 0);
    __syncthreads();
  }
  int q = lane >> 4, l16 = lane & 15;
  for (int i = 0; i < 4; ++i)
    for (int j = 0; j < 4; ++j) {
      int col = wc * 64 + j * 16 + l16;
      float bb = b2f(b_node[col]);
      for (int rr = 0; rr < 4; ++rr) {
        int row = wr * 64 + i * 16 + q * 4 + rr;
        sm.C[row][col] = f2b(fmaxf(acc[i][j][rr] + bb, 0.f));
      }
    }
  __syncthreads();
  {
    int r = tid >> 1, h = (tid & 1) * 64;
    int rg = r0 + r;
    if (rg < nrows) {
      uint4* po = (uint4*)(HNF + (size_t)rg * 128 + h);
      for (int k = 0; k < 8; ++k) {
        unsigned int a0 = *(const unsigned int*)&sm.C[r][h + k * 8];
        unsigned int a1 = *(const unsigned int*)&sm.C[r][h + k * 8 + 2];
        unsigned int a2 = *(const unsigned int*)&sm.C[r][h + k * 8 + 4];
        unsigned int a3 = *(const unsigned int*)&sm.C[r][h + k * 8 + 6];
        po[k] = make_uint4(a0, a1, a2, a3);
      }
    }
  }
}

// ---------------- output heads (MFMA, fp32 output, optional row remap) ----------------
__global__ __launch_bounds__(256)
void head_kernel(const u16* IN, const u16* WT, const u16* bias, float* OUT, long R,
                 const int* remap) {
  __shared__ __align__(16) u16 Asm[128][40];
  __shared__ __align__(16) u16 Bsm[32][40];
  int blk = blockIdx.x, tid = threadIdx.x;
  int lane = tid & 63, wv = tid >> 6;
  f32x4 acc[2][2];
  f32x4 zf = {0.f, 0.f, 0.f, 0.f};
  for (int i = 0; i < 2; ++i) for (int j = 0; j < 2; ++j) acc[i][j] = zf;
  int arow = tid >> 1, ahalf = (tid & 1) * 16;
  long r0 = (long)blk * 128;
  for (int kc = 0; kc < 4; ++kc) {
    {
      long r = r0 + arow;
      uint4 v0 = make_uint4(0, 0, 0, 0), v1 = make_uint4(0, 0, 0, 0);
      if (r < R) {
        const uint4* p = (const uint4*)(IN + r * 128 + kc * 32 + ahalf);
        v0 = p[0]; v1 = p[1];
      }
      *(uint4*)&Asm[arow][ahalf] = v0;
      *(uint4*)&Asm[arow][ahalf + 8] = v1;
    }
    if (tid < 64) {
      const uint4* p = (const uint4*)(WT + arow * 128 + kc * 32 + ahalf);
      uint4 v0 = p[0], v1 = p[1];
      *(uint4*)&Bsm[arow][ahalf] = v0;
      *(uint4*)&Bsm[arow][ahalf + 8] = v1;
    }
    __syncthreads();
    int q = lane >> 4, l16 = lane & 15;
    bf16x8 af[2], bfr[2];
    for (int i = 0; i < 2; ++i) af[i] = *(const bf16x8*)&Asm[wv * 32 + i * 16 + l16][q * 8];
    for (int j = 0; j < 2; ++j) bfr[j] = *(const bf16x8*)&Bsm[j * 16 + l16][q * 8];
    for (int i = 0; i < 2; ++i)
      for (int j = 0; j < 2; ++j)
        acc[i][j] = __builtin_amdgcn_mfma_f32_16x16x32_bf16(af[i], bfr[j], acc[i][j], 0, 0, 0);
    __syncthreads();
  }
  int q = lane >> 4, l16 = lane & 15;
  for (int i = 0; i < 2; ++i)
    for (int rr = 0; rr < 4; ++rr) {
      long r = r0 + wv * 32 + i * 16 + q * 4 + rr;
      if (r < R) {
        long ro = remap ? (long)remap[r] : r;
        for (int j = 0; j < 2; ++j) {
          int col = j * 16 + l16;
          OUT[ro * 32 + col] = acc[i][j][rr] + b2f(bias[col]);
        }
      }
    }
}

extern "C" void kernel_launch(void* const* d_in, const int* in_sizes, int n_in,
                              void* d_out, int out_size, void* d_ws, size_t ws_size,
                              hipStream_t stream) {
  const size_t REQUIRED = 160000000;
  if (ws_size < REQUIRED) return;

  const void* nf_r = d_in[0];
  const void* ef_r = d_in[1];
  const int* src = (const int*)d_in[2];
  const int* dst = (const int*)d_in[3];

  char* ws = (char*)d_ws;
  auto alloc = [&](size_t bytes) {
    char* p = ws;
    ws += (bytes + 255) & ~(size_t)255;
    return p;
  };
  u16* HEF = (u16*)alloc((size_t)GE * 128 * 2);
  u16* HNF = (u16*)alloc((size_t)GN * 128 * 2);
  u16* Xs = (u16*)alloc((size_t)GN * 128 * 2);
  u16* Xd = (u16*)alloc((size_t)GN * 128 * 2);
  float* as_ = (float*)alloc((size_t)GN * 4);
  float* ad_ = (float*)alloc((size_t)GN * 4);
  float* logit = (float*)alloc((size_t)GE * 4);
  int* rowptr = (int*)alloc((size_t)(GN + 1) * 4);
  int* cursor = (int*)alloc((size_t)GN * 4);
  int* eid = (int*)alloc((size_t)GE * 4);
  int* srcs = (int*)alloc((size_t)GE * 4);
  int* dsts = (int*)alloc((size_t)GE * 4);
  u16* WeT = (u16*)alloc(128 * 160 * 2);
  u16* WnpT = (u16*)alloc(256 * 160 * 2);
  u16* WnuT = (u16*)alloc(128 * 288 * 2);
  u16* WoN = (u16*)alloc(32 * 128 * 2);
  u16* WoE = (u16*)alloc(32 * 128 * 2);
  u16* nfc = (u16*)alloc((size_t)GN * 32 * 2);
  u16* efc = (u16*)alloc((size_t)GE * 32 * 2);
  u16* bec = (u16*)alloc(128 * 2);
  u16* Wac = (u16*)alloc(480 * 2);
  u16* bac = (u16*)alloc(2);
  u16* bnc = (u16*)alloc(128 * 2);
  u16* bnoc = (u16*)alloc(32 * 2);
  u16* beoc = (u16*)alloc(32 * 2);
  int* dflag = (int*)alloc(4);
  u16* AGG = Xs;  // overlay: Xs (bf16, 6.4MB) dead after edge stage; AGG consumed
                  // by node_update before next iter's node_proj rewrites Xs

  detect_dtype<<<1, 64, 0, stream>>>(nf_r, dflag);
  // CSR build first (gathers depend on eid)
  hipMemsetAsync(cursor, 0, (size_t)GN * 4, stream);
  hist_kernel<<<1563, 256, 0, stream>>>(dst, cursor, GE);
  scan_kernel<<<1, 256, 0, stream>>>(cursor, rowptr, GN);
  fill_kernel<<<1563, 256, 0, stream>>>(src, dst, cursor, eid, srcs, dsts, GE);

  convert_kernel<<<784, 256, 0, stream>>>(nf_r, nfc, (long)GN * 32, dflag);
  gather_ef<<<6250, 256, 0, stream>>>(ef_r, eid, efc, dflag);
  prep_weights<<<128, 256, 0, stream>>>(d_in[4], d_in[8], d_in[6], d_in[10], d_in[12],
                                        d_in[5], d_in[7], d_in[9], d_in[11], d_in[13],
                                        WeT, WnpT, WnuT, WoN, WoE,
                                        Wac, bec, bac, bnc, bnoc, beoc, dflag);

  for (int iter = 0; iter < 3; ++iter) {
    int kc0 = (iter == 0) ? 4 : 0;
    dim3 npgrid(NODE_BLKS, 2);
    node_proj<<<npgrid, 256, 0, stream>>>(HNF, nfc, WnpT, Wac, Xs, Xd, as_, ad_, kc0, GN);
    if (iter == 0)
      edge_fused<4><<<EDGE_BLKS, 256, 0, stream>>>(HEF, efc, WeT, Wac, bec, bac, srcs, dsts,
                                                   Xs, Xd, as_, ad_, logit);
    else
      edge_fused<0><<<EDGE_BLKS, 256, 0, stream>>>(HEF, efc, WeT, Wac, bec, bac, srcs, dsts,
                                                   Xs, Xd, as_, ad_, logit);
    aggregate<<<(GN + 3) / 4, 256, 0, stream>>>(rowptr, logit, HEF, AGG, GN);
    node_update<<<NODE_BLKS, 256, 0, stream>>>(HNF, nfc, AGG, WnuT, bnc, kc0, GN);
  }

  float* out_nf = (float*)d_out;
  float* out_ef = (float*)d_out + (size_t)GN * 32;
  head_kernel<<<NODE_BLKS, 256, 0, stream>>>(HNF, WoN, bnoc, out_nf, GN, nullptr);
  head_kernel<<<HEAD_EBLKS, 256, 0, stream>>>(HEF, WoE, beoc, out_ef, GE, eid);
}

// Round 4
// 655.839 us; speedup vs baseline: 1.0803x; 1.0803x over previous
//
#include <hip/hip_runtime.h>

// IJGNN attention-MPNN, 3 iterations. fp32 in/out, bf16 internal.
// Edges processed in dst-sorted (CSR) order; edge head scatters back via eid.
// This rev: edge_fused = round-2 skeleton + (a) B fragments direct from L2-hot
// WeT with 2-deep ping-pong registers (bfp[2][4], 32 VGPR -- NOT all 5 chunks,
// which spilled in round 3 and doubled HBM traffic), (b) A chunk 1-deep reg
// prefetch into double-buffered LDS -> 1 barrier/chunk, (c) no B LDS staging.

#define GN 25000
#define GE 400000
#define NODE_BLKS 196    // ceil(GN/128)
#define EDGE_BLKS 6250   // GE/64 exact (edge_fused tiles)
#define HEAD_EBLKS 3125  // GE/128 exact (head_kernel tiles)

typedef unsigned short u16;
typedef __attribute__((ext_vector_type(8))) short bf16x8;
typedef __attribute__((ext_vector_type(4))) float f32x4;

__device__ inline float b2f(u16 v) {
  union { unsigned int u; float f; } x; x.u = ((unsigned int)v) << 16; return x.f;
}
__device__ inline u16 f2b(float f) {
  union { float f; unsigned int u; } x; x.f = f;
  unsigned int u = x.u;
  u += 0x7fffu + ((u >> 16) & 1u);
  return (u16)(u >> 16);
}

// ---------------- dtype probe + convert ----------------
__global__ void detect_dtype(const void* nf, int* flag) {
  if (blockIdx.x == 0 && threadIdx.x == 0) {
    const u16* p = (const u16*)nf;
    int cnt = 0;
    for (int i = 0; i < 512; i += 2) {
      int e = (p[i] >> 7) & 0xFF;
      if (e >= 0x70 && e <= 0x85) cnt++;
    }
    *flag = (cnt < 128) ? 1 : 0;
  }
}

__global__ void convert_kernel(const void* src, u16* dst, long n, const int* flag) {
  int f32 = *flag;
  long i = (long)blockIdx.x * blockDim.x + threadIdx.x;
  long stride = (long)gridDim.x * blockDim.x;
  for (; i < n; i += stride)
    dst[i] = f32 ? f2b(((const float*)src)[i]) : ((const u16*)src)[i];
}

// gather ef rows into dst-sorted order (+convert)
__global__ void gather_ef(const void* ef, const int* eid, u16* efc, const int* flag) {
  int f32 = *flag;
  long idx = (long)blockIdx.x * blockDim.x + threadIdx.x;
  long stride = (long)gridDim.x * blockDim.x;
  long ntot = (long)GE * 32;
  for (; idx < ntot; idx += stride) {
    long j = idx >> 5;
    int c = (int)(idx & 31);
    long e = eid[j];
    efc[idx] = f32 ? f2b(((const float*)ef)[e * 32 + c]) : ((const u16*)ef)[e * 32 + c];
  }
}

// ---------------- weight prep: convert (raw f32/bf16) + transpose, one launch ----------------
__global__ void prep_weights(const void* We, const void* Wn, const void* Wa,
                             const void* Won, const void* Woe,
                             const void* be, const void* ba, const void* bn,
                             const void* bno, const void* beo,
                             u16* WeT, u16* WnpT, u16* WnuT, u16* WoN, u16* WoE,
                             u16* Wac, u16* bec, u16* bac, u16* bnc, u16* bnoc, u16* beoc,
                             const int* flag) {
  int f32 = *flag;
  auto ld = [&](const void* p, long i) -> u16 {
    return f32 ? f2b(((const float*)p)[i]) : ((const u16*)p)[i];
  };
  int tid = blockIdx.x * blockDim.x + threadIdx.x;
  int nt = gridDim.x * blockDim.x;
  for (int i = tid; i < 128 * 160; i += nt) { int n = i / 160, k = i % 160; WeT[i] = ld(We, (long)(320 + k) * 128 + n); }
  for (int i = tid; i < 256 * 160; i += nt) {
    int c = i / 160, k = i % 160;
    WnpT[i] = (c < 128) ? ld(We, (long)k * 128 + c) : ld(We, (long)(160 + k) * 128 + (c - 128));
  }
  for (int i = tid; i < 128 * 288; i += nt) { int c = i / 288, k = i % 288; WnuT[i] = ld(Wn, (long)k * 128 + c); }
  for (int i = tid; i < 32 * 128; i += nt) {
    int c = i / 128, k = i % 128;
    WoN[i] = ld(Won, (long)k * 32 + c);
    WoE[i] = ld(Woe, (long)k * 32 + c);
  }
  for (int i = tid; i < 480; i += nt) Wac[i] = ld(Wa, i);
  for (int i = tid; i < 128; i += nt) { bec[i] = ld(be, i); bnc[i] = ld(bn, i); }
  for (int i = tid; i < 32; i += nt) { bnoc[i] = ld(bno, i); beoc[i] = ld(beo, i); }
  if (tid == 0) bac[0] = ld(ba, 0);
}

// ---------------- CSR build ----------------
__global__ void hist_kernel(const int* dst, int* counts, int n) {
  for (int e = blockIdx.x * blockDim.x + threadIdx.x; e < n; e += gridDim.x * blockDim.x)
    atomicAdd(&counts[dst[e]], 1);
}

__global__ __launch_bounds__(256) void scan_kernel(int* cursor, int* rowptr, int n) {
  __shared__ int part[256];
  int t = threadIdx.x;
  int per = (n + 255) / 256;
  int lo = t * per;
  int hi = lo + per; if (hi > n) hi = n;
  if (lo > n) lo = n;
  int s = 0;
  for (int i = lo; i < hi; ++i) s += cursor[i];
  part[t] = s;
  __syncthreads();
  for (int off = 1; off < 256; off <<= 1) {
    int v = (t >= off) ? part[t - off] : 0;
    __syncthreads();
    part[t] += v;
    __syncthreads();
  }
  int run = (t > 0) ? part[t - 1] : 0;
  for (int i = lo; i < hi; ++i) {
    int c = cursor[i];
    cursor[i] = run;
    rowptr[i + 1] = run + c;
    run += c;
  }
  if (t == 0) rowptr[0] = 0;
}

// fill CSR order + gather src/dst meta in the same pass
__global__ void fill_kernel(const int* src, const int* dst, int* cursor, int* eid,
                            int* srcs, int* dsts, int n) {
  for (int e = blockIdx.x * blockDim.x + threadIdx.x; e < n; e += gridDim.x * blockDim.x) {
    int d = dst[e];
    int p = atomicAdd(&cursor[d], 1);
    eid[p] = e;
    srcs[p] = src[e];
    dsts[p] = d;
  }
}

// ---------------- node projections (MFMA): Xs/Xd [N,128] bf16, as/ad [N] fp32 ----------------
__global__ __launch_bounds__(256)
void node_proj(const u16* HNF, const u16* nf, const u16* WnpT, const u16* W_attn,
               u16* Xs, u16* Xd, float* as_, float* ad_, int kc0, int nrows) {
  __shared__ union {
    struct { __align__(16) u16 A[128][40]; __align__(16) u16 B[128][40]; } st;
    u16 C[128][130];  // bf16 transpose buffer (final values; no extra rounding)
  } sm;
  __shared__ float dotbuf[128][2];
  int sel = blockIdx.y, blk = blockIdx.x, tid = threadIdx.x;
  int lane = tid & 63, wv = tid >> 6, wr = wv & 1, wc = wv >> 1;
  const u16* BT = WnpT + sel * 128 * 160;
  u16* OUT = sel ? Xd : Xs;
  float* AOUT = sel ? ad_ : as_;
  const u16* wa = W_attn + sel * 160;
  f32x4 acc[4][4];
  f32x4 zf = {0.f, 0.f, 0.f, 0.f};
  for (int i = 0; i < 4; ++i) for (int j = 0; j < 4; ++j) acc[i][j] = zf;
  float dp = 0.f;
  int arow = tid >> 1, ahalf = (tid & 1) * 16;
  int r0 = blk * 128;
  for (int kc = kc0; kc < 5; ++kc) {
    {
      int r = r0 + arow;
      uint4 v0 = make_uint4(0, 0, 0, 0), v1 = make_uint4(0, 0, 0, 0);
      if (r < nrows) {
        const uint4* p = (kc < 4) ? (const uint4*)(HNF + (size_t)r * 128 + kc * 32 + ahalf)
                                  : (const uint4*)(nf + (size_t)r * 32 + ahalf);
        v0 = p[0]; v1 = p[1];
      }
      *(uint4*)&sm.st.A[arow][ahalf] = v0;
      *(uint4*)&sm.st.A[arow][ahalf + 8] = v1;
    }
    {
      const uint4* p = (const uint4*)(BT + arow * 160 + kc * 32 + ahalf);
      uint4 v0 = p[0], v1 = p[1];
      *(uint4*)&sm.st.B[arow][ahalf] = v0;
      *(uint4*)&sm.st.B[arow][ahalf + 8] = v1;
    }
    __syncthreads();
    {
      float s = 0.f;
      for (int j = 0; j < 16; ++j) s += b2f(sm.st.A[arow][ahalf + j]) * b2f(wa[kc * 32 + ahalf + j]);
      dp += s;
    }
    int q = lane >> 4, l16 = lane & 15;
    bf16x8 af[4], bfr[4];
    for (int i = 0; i < 4; ++i) af[i] = *(const bf16x8*)&sm.st.A[wr * 64 + i * 16 + l16][q * 8];
    for (int j = 0; j < 4; ++j) bfr[j] = *(const bf16x8*)&sm.st.B[wc * 64 + j * 16 + l16][q * 8];
    for (int i = 0; i < 4; ++i)
      for (int j = 0; j < 4; ++j)
        acc[i][j] = __builtin_amdgcn_mfma_f32_16x16x32_bf16(af[i], bfr[j], acc[i][j], 0, 0, 0);
    __syncthreads();
  }
  dotbuf[arow][tid & 1] = dp;
  // scatter acc -> LDS transpose buffer (overlays staging; K-loop is done)
  {
    int q = lane >> 4, l16 = lane & 15;
    for (int i = 0; i < 4; ++i)
      for (int j = 0; j < 4; ++j) {
        int col = wc * 64 + j * 16 + l16;
        for (int rr = 0; rr < 4; ++rr) {
          int row = wr * 64 + i * 16 + q * 4 + rr;
          sm.C[row][col] = f2b(acc[i][j][rr]);
        }
      }
  }
  __syncthreads();
  if (tid < 128) {
    int r = r0 + tid;
    if (r < nrows) AOUT[r] = dotbuf[tid][0] + dotbuf[tid][1];
  }
  // vectorized store: each thread owns one row-half (64 cols = 8x dwordx4)
  {
    int r = tid >> 1, h = (tid & 1) * 64;
    int rg = r0 + r;
    if (rg < nrows) {
      uint4* po = (uint4*)(OUT + (size_t)rg * 128 + h);
      for (int k = 0; k < 8; ++k) {
        unsigned int a0 = *(const unsigned int*)&sm.C[r][h + k * 8];
        unsigned int a1 = *(const unsigned int*)&sm.C[r][h + k * 8 + 2];
        unsigned int a2 = *(const unsigned int*)&sm.C[r][h + k * 8 + 4];
        unsigned int a3 = *(const unsigned int*)&sm.C[r][h + k * 8 + 6];
        po[k] = make_uint4(a0, a1, a2, a3);
      }
    }
  }
}

// ---------------- edge stage: 64-edge tiles, A dbuf LDS, B frags from L2 (ping-pong) ----------------
// Per K-chunk: {A reg->LDS(dbuf), 1-deep A+B prefetch, 1 barrier, 2 LDS A-frag
// reads, 8 MFMA}. B never touches LDS (L2-hot 40KB WeT). bfp[2][4] ping-pong
// keeps B liveness at 32 VGPR (round-3's bf[5][4]=80 VGPR spilled to scratch:
// WRITE_SIZE 101->227MB). Epilogue: two 64-col passes through f32 LDS transpose
// (no extra rounding), vector gathers of Xs/Xd + vector HEF stores.
template <int KC0>
__global__ __launch_bounds__(256, 4)
void edge_fused(u16* HEF, const u16* ef, const u16* WeT, const u16* W_attn,
                const u16* b_edge, const u16* b_attn, const int* srcs, const int* dsts,
                const u16* Xs, const u16* Xd, const float* as_, const float* ad_,
                float* logit) {
  __shared__ union {
    __align__(16) u16 A[2][64][40];  // double-buffered A chunk (10.2KB)
    float C[64][65];                 // epilogue transpose (16.6KB); bank spread
  } sm;
  __shared__ float dotbuf[64];
  int blk = blockIdx.x, tid = threadIdx.x;
  int lane = tid & 63, wv = tid >> 6, wr = wv & 1, wc = wv >> 1;
  int q = lane >> 4, l16 = lane & 15;
  f32x4 acc[2][4];
  f32x4 zf = {0.f, 0.f, 0.f, 0.f};
  for (int i = 0; i < 2; ++i) for (int j = 0; j < 4; ++j) acc[i][j] = zf;
  float dp[2] = {0.f, 0.f};
  long e0 = (long)blk * 64;
  long ea = e0 + (tid >> 2);
  int qp = (tid & 3) * 8;  // A col offset (u16 units), 16B per thread
  const u16* wa = W_attn + 320;

  // 1-deep prefetch: A chunk to a single reg quad, B frags ping-pong (2x4 frags)
  uint4 va = (KC0 < 4) ? *(const uint4*)(HEF + ea * 128 + KC0 * 32 + qp)
                       : *(const uint4*)(ef + ea * 32 + qp);
  bf16x8 bfp[2][4];
#pragma unroll
  for (int j = 0; j < 4; ++j)
    bfp[KC0 & 1][j] = *(const bf16x8*)(WeT + (size_t)(wc * 64 + j * 16 + l16) * 160 + KC0 * 32 + q * 8);

#pragma unroll
  for (int kc = KC0; kc < 5; ++kc) {
    int buf = kc & 1;
    *(uint4*)&sm.A[buf][tid >> 2][qp] = va;
    if (kc < 4) {  // issue next-chunk loads; latency hides under barrier+MFMA
      va = (kc + 1 < 4) ? *(const uint4*)(HEF + ea * 128 + (kc + 1) * 32 + qp)
                        : *(const uint4*)(ef + ea * 32 + qp);
#pragma unroll
      for (int j = 0; j < 4; ++j)
        bfp[(kc + 1) & 1][j] = *(const bf16x8*)(WeT + (size_t)(wc * 64 + j * 16 + l16) * 160 + (kc + 1) * 32 + q * 8);
    }
    __syncthreads();
    bf16x8 af[2];
    for (int i = 0; i < 2; ++i) af[i] = *(const bf16x8*)&sm.A[buf][wr * 32 + i * 16 + l16][q * 8];
    if (wc == 0) {
      bf16x8 wv8 = *(const bf16x8*)&wa[kc * 32 + q * 8];
      float wf[8];
      for (int j = 0; j < 8; ++j) wf[j] = b2f((u16)wv8[j]);
      for (int i = 0; i < 2; ++i)
        for (int j = 0; j < 8; ++j) dp[i] += b2f((u16)af[i][j]) * wf[j];
    }
    for (int i = 0; i < 2; ++i)
      for (int j = 0; j < 4; ++j)
        acc[i][j] = __builtin_amdgcn_mfma_f32_16x16x32_bf16(af[i], bfp[buf][j], acc[i][j], 0, 0, 0);
  }
  if (wc == 0) {
    for (int i = 0; i < 2; ++i) {
      dp[i] += __shfl_xor(dp[i], 16);
      dp[i] += __shfl_xor(dp[i], 32);
    }
    if (q == 0)
      for (int i = 0; i < 2; ++i) dotbuf[wr * 32 + i * 16 + l16] = dp[i];
  }
  int r = tid >> 2, qh = tid & 3;  // each thread: one edge row, 16 cols/pass
  long e = e0 + r;
  int s = srcs[e], d = dsts[e];
#pragma unroll
  for (int p = 0; p < 2; ++p) {
    int cb = p * 64 + qh * 16;
    // issue vector gathers early: latency hides under barrier + LDS scatter
    const uint4* ps = (const uint4*)(Xs + (size_t)s * 128 + cb);
    const uint4* pd = (const uint4*)(Xd + (size_t)d * 128 + cb);
    uint4 gs0 = ps[0], gs1 = ps[1], gd0 = pd[0], gd1 = pd[1];
    // p=0: wait for all waves' last A-reads + dotbuf writes before overlaying C
    // p=1: wait for pass-0 C reads before rewriting C
    __syncthreads();
    if (wc == p) {  // this wave pair's acc covers cols [p*64, p*64+64)
      for (int i = 0; i < 2; ++i)
        for (int j = 0; j < 4; ++j) {
          int col = j * 16 + l16;
          float bb = b2f(b_edge[p * 64 + col]);
          for (int rr = 0; rr < 4; ++rr)
            sm.C[wr * 32 + i * 16 + q * 4 + rr][col] = acc[i][j][rr] + bb;
        }
    }
    __syncthreads();
    if (p == 0 && tid < 64) {
      long ee = e0 + tid;
      logit[ee] = dotbuf[tid] + as_[srcs[ee]] + ad_[dsts[ee]] + b2f(b_attn[0]);
    }
    unsigned int us[8], ud[8];
    *(uint4*)&us[0] = gs0; *(uint4*)&us[4] = gs1;
    *(uint4*)&ud[0] = gd0; *(uint4*)&ud[4] = gd1;
    unsigned int ov[8];
    for (int w = 0; w < 8; ++w) {
      float c0 = sm.C[r][qh * 16 + 2 * w];
      float c1 = sm.C[r][qh * 16 + 2 * w + 1];
      float v0 = c0 + b2f((u16)(us[w] & 0xffffu)) + b2f((u16)(ud[w] & 0xffffu));
      float v1 = c1 + b2f((u16)(us[w] >> 16)) + b2f((u16)(ud[w] >> 16));
      ov[w] = (unsigned int)f2b(fmaxf(v0, 0.f)) | ((unsigned int)f2b(fmaxf(v1, 0.f)) << 16);
    }
    uint4* po = (uint4*)(HEF + e * 128 + cb);
    po[0] = *(uint4*)&ov[0];
    po[1] = *(uint4*)&ov[4];
  }
}

// ---------------- per-dst softmax + aggregation ----------------
// 1 wave per dst row; 8 edges/iteration: lane = (edge-slot sub, col-group cl),
// 32B/lane M reads, 3-level shfl_xor fold over the 8 edge-slots.
__global__ __launch_bounds__(256)
void aggregate(const int* rowptr, const float* logit, const u16* M, u16* AGG, int nrows) {
  int gw = (blockIdx.x * blockDim.x + threadIdx.x) >> 6;
  int lane = threadIdx.x & 63;
  if (gw >= nrows) return;
  int beg = rowptr[gw], end = rowptr[gw + 1];
  int sub = lane >> 3, cl = lane & 7;
  float mx = -1e30f;
  for (int j = beg + lane; j < end; j += 64) mx = fmaxf(mx, logit[j]);
  for (int off = 32; off > 0; off >>= 1) mx = fmaxf(mx, __shfl_xor(mx, off));
  float acc[16];
  for (int t = 0; t < 16; ++t) acc[t] = 0.f;
  float denom = 0.f;
  for (int j0 = beg; j0 < end; j0 += 8) {
    int j = j0 + sub;
    float w = 0.f;
    uint4 m0 = make_uint4(0, 0, 0, 0), m1 = make_uint4(0, 0, 0, 0);
    if (j < end) {
      w = __expf(logit[j] - mx);
      const uint4* mp = (const uint4*)(M + (size_t)j * 128 + cl * 16);
      m0 = mp[0]; m1 = mp[1];
    }
    denom += w;
    const unsigned int* mw0 = (const unsigned int*)&m0;
    const unsigned int* mw1 = (const unsigned int*)&m1;
    for (int t = 0; t < 4; ++t) {
      acc[2 * t]     += w * b2f((u16)(mw0[t] & 0xffffu));
      acc[2 * t + 1] += w * b2f((u16)(mw0[t] >> 16));
      acc[8 + 2 * t]     += w * b2f((u16)(mw1[t] & 0xffffu));
      acc[8 + 2 * t + 1] += w * b2f((u16)(mw1[t] >> 16));
    }
  }
  denom += __shfl_xor(denom, 8);
  denom += __shfl_xor(denom, 16);
  denom += __shfl_xor(denom, 32);
  for (int t = 0; t < 16; ++t) {
    acc[t] += __shfl_xor(acc[t], 8);
    acc[t] += __shfl_xor(acc[t], 16);
    acc[t] += __shfl_xor(acc[t], 32);
  }
  float inv = 1.0f / fmaxf(denom, 1e-16f);
  if (sub == 0) {
    unsigned int ov[8];
    for (int t = 0; t < 8; ++t)
      ov[t] = (unsigned int)f2b(acc[2 * t] * inv) | ((unsigned int)f2b(acc[2 * t + 1] * inv) << 16);
    uint4* po = (uint4*)(AGG + (size_t)gw * 128 + cl * 16);
    po[0] = *(uint4*)&ov[0];
    po[1] = *(uint4*)&ov[4];
  }
}

// ---------------- node update (MFMA, in-place HNF) ----------------
__global__ __launch_bounds__(256)
void node_update(u16* HNF, const u16* nf, const u16* AGG, const u16* WnuT,
                 const u16* b_node, int kc0, int nrows) {
  __shared__ union {
    struct { __align__(16) u16 A[128][40]; __align__(16) u16 B[128][40]; } st;
    u16 C[128][130];
  } sm;
  int blk = blockIdx.x, tid = threadIdx.x;
  int lane = tid & 63, wv = tid >> 6, wr = wv & 1, wc = wv >> 1;
  f32x4 acc[4][4];
  f32x4 zf = {0.f, 0.f, 0.f, 0.f};
  for (int i = 0; i < 4; ++i) for (int j = 0; j < 4; ++j) acc[i][j] = zf;
  int arow = tid >> 1, ahalf = (tid & 1) * 16;
  int r0 = blk * 128;
  for (int kc = kc0; kc < 9; ++kc) {
    {
      int r = r0 + arow;
      uint4 v0 = make_uint4(0, 0, 0, 0), v1 = make_uint4(0, 0, 0, 0);
      if (r < nrows) {
        const u16* p;
        if (kc < 4) p = HNF + (size_t)r * 128 + kc * 32 + ahalf;
        else if (kc == 4) p = nf + (size_t)r * 32 + ahalf;
        else p = AGG + (size_t)r * 128 + (kc - 5) * 32 + ahalf;
        v0 = ((const uint4*)p)[0];
        v1 = ((const uint4*)p)[1];
      }
      *(uint4*)&sm.st.A[arow][ahalf] = v0;
      *(uint4*)&sm.st.A[arow][ahalf + 8] = v1;
    }
    {
      const uint4* p = (const uint4*)(WnuT + arow * 288 + kc * 32 + ahalf);
      uint4 v0 = p[0], v1 = p[1];
      *(uint4*)&sm.st.B[arow][ahalf] = v0;
      *(uint4*)&sm.st.B[arow][ahalf + 8] = v1;
    }
    __syncthreads();
    int q = lane >> 4, l16 = lane & 15;
    bf16x8 af[4], bfr[4];
    for (int i = 0; i < 4; ++i) af[i] = *(const bf16x8*)&sm.st.A[wr * 64 + i * 16 + l16][q * 8];
    for (int j = 0; j < 4; ++j) bfr[j] = *(const bf16x8*)&sm.st.B[wc * 64 + j * 16 + l16][q * 8];
    for (int i = 0; i < 4; ++i)
      for (int j = 0; j < 4; ++j)
        acc[i][j] = __builtin_amdgcn_mfma_f32_16x16x32_bf16(af[i], bfr[j], acc[i][j], 0, 0, 0);
    __syncthreads();
  }
  int q = lane >> 4, l16 = lane & 15;
  for (int i = 0; i < 4; ++i)
    for (int j = 0; j < 4; ++j) {
      int col = wc * 64 + j * 16 + l16;
      float bb = b2f(b_node[col]);
      for (int rr = 0; rr < 4; ++rr) {
        int row = wr * 64 + i * 16 + q * 4 + rr;
        sm.C[row][col] = f2b(fmaxf(acc[i][j][rr] + bb, 0.f));
      }
    }
  __syncthreads();
  {
    int r = tid >> 1, h = (tid & 1) * 64;
    int rg = r0 + r;
    if (rg < nrows) {
      uint4* po = (uint4*)(HNF + (size_t)rg * 128 + h);
      for (int k = 0; k < 8; ++k) {
        unsigned int a0 = *(const unsigned int*)&sm.C[r][h + k * 8];
        unsigned int a1 = *(const unsigned int*)&sm.C[r][h + k * 8 + 2];
        unsigned int a2 = *(const unsigned int*)&sm.C[r][h + k * 8 + 4];
        unsigned int a3 = *(const unsigned int*)&sm.C[r][h + k * 8 + 6];
        po[k] = make_uint4(a0, a1, a2, a3);
      }
    }
  }
}

// ---------------- output heads (MFMA, fp32 output, optional row remap) ----------------
__global__ __launch_bounds__(256)
void head_kernel(const u16* IN, const u16* WT, const u16* bias, float* OUT, long R,
                 const int* remap) {
  __shared__ __align__(16) u16 Asm[128][40];
  __shared__ __align__(16) u16 Bsm[32][40];
  int blk = blockIdx.x, tid = threadIdx.x;
  int lane = tid & 63, wv = tid >> 6;
  f32x4 acc[2][2];
  f32x4 zf = {0.f, 0.f, 0.f, 0.f};
  for (int i = 0; i < 2; ++i) for (int j = 0; j < 2; ++j) acc[i][j] = zf;
  int arow = tid >> 1, ahalf = (tid & 1) * 16;
  long r0 = (long)blk * 128;
  for (int kc = 0; kc < 4; ++kc) {
    {
      long r = r0 + arow;
      uint4 v0 = make_uint4(0, 0, 0, 0), v1 = make_uint4(0, 0, 0, 0);
      if (r < R) {
        const uint4* p = (const uint4*)(IN + r * 128 + kc * 32 + ahalf);
        v0 = p[0]; v1 = p[1];
      }
      *(uint4*)&Asm[arow][ahalf] = v0;
      *(uint4*)&Asm[arow][ahalf + 8] = v1;
    }
    if (tid < 64) {
      const uint4* p = (const uint4*)(WT + arow * 128 + kc * 32 + ahalf);
      uint4 v0 = p[0], v1 = p[1];
      *(uint4*)&Bsm[arow][ahalf] = v0;
      *(uint4*)&Bsm[arow][ahalf + 8] = v1;
    }
    __syncthreads();
    int q = lane >> 4, l16 = lane & 15;
    bf16x8 af[2], bfr[2];
    for (int i = 0; i < 2; ++i) af[i] = *(const bf16x8*)&Asm[wv * 32 + i * 16 + l16][q * 8];
    for (int j = 0; j < 2; ++j) bfr[j] = *(const bf16x8*)&Bsm[j * 16 + l16][q * 8];
    for (int i = 0; i < 2; ++i)
      for (int j = 0; j < 2; ++j)
        acc[i][j] = __builtin_amdgcn_mfma_f32_16x16x32_bf16(af[i], bfr[j], acc[i][j], 0, 0, 0);
    __syncthreads();
  }
  int q = lane >> 4, l16 = lane & 15;
  for (int i = 0; i < 2; ++i)
    for (int rr = 0; rr < 4; ++rr) {
      long r = r0 + wv * 32 + i * 16 + q * 4 + rr;
      if (r < R) {
        long ro = remap ? (long)remap[r] : r;
        for (int j = 0; j < 2; ++j) {
          int col = j * 16 + l16;
          OUT[ro * 32 + col] = acc[i][j][rr] + b2f(bias[col]);
        }
      }
    }
}

extern "C" void kernel_launch(void* const* d_in, const int* in_sizes, int n_in,
                              void* d_out, int out_size, void* d_ws, size_t ws_size,
                              hipStream_t stream) {
  const size_t REQUIRED = 160000000;
  if (ws_size < REQUIRED) return;

  const void* nf_r = d_in[0];
  const void* ef_r = d_in[1];
  const int* src = (const int*)d_in[2];
  const int* dst = (const int*)d_in[3];

  char* ws = (char*)d_ws;
  auto alloc = [&](size_t bytes) {
    char* p = ws;
    ws += (bytes + 255) & ~(size_t)255;
    return p;
  };
  u16* HEF = (u16*)alloc((size_t)GE * 128 * 2);
  u16* HNF = (u16*)alloc((size_t)GN * 128 * 2);
  u16* Xs = (u16*)alloc((size_t)GN * 128 * 2);
  u16* Xd = (u16*)alloc((size_t)GN * 128 * 2);
  float* as_ = (float*)alloc((size_t)GN * 4);
  float* ad_ = (float*)alloc((size_t)GN * 4);
  float* logit = (float*)alloc((size_t)GE * 4);
  int* rowptr = (int*)alloc((size_t)(GN + 1) * 4);
  int* cursor = (int*)alloc((size_t)GN * 4);
  int* eid = (int*)alloc((size_t)GE * 4);
  int* srcs = (int*)alloc((size_t)GE * 4);
  int* dsts = (int*)alloc((size_t)GE * 4);
  u16* WeT = (u16*)alloc(128 * 160 * 2);
  u16* WnpT = (u16*)alloc(256 * 160 * 2);
  u16* WnuT = (u16*)alloc(128 * 288 * 2);
  u16* WoN = (u16*)alloc(32 * 128 * 2);
  u16* WoE = (u16*)alloc(32 * 128 * 2);
  u16* nfc = (u16*)alloc((size_t)GN * 32 * 2);
  u16* efc = (u16*)alloc((size_t)GE * 32 * 2);
  u16* bec = (u16*)alloc(128 * 2);
  u16* Wac = (u16*)alloc(480 * 2);
  u16* bac = (u16*)alloc(2);
  u16* bnc = (u16*)alloc(128 * 2);
  u16* bnoc = (u16*)alloc(32 * 2);
  u16* beoc = (u16*)alloc(32 * 2);
  int* dflag = (int*)alloc(4);
  u16* AGG = Xs;  // overlay: Xs (bf16, 6.4MB) dead after edge stage; AGG consumed
                  // by node_update before next iter's node_proj rewrites Xs

  detect_dtype<<<1, 64, 0, stream>>>(nf_r, dflag);
  // CSR build first (gathers depend on eid)
  hipMemsetAsync(cursor, 0, (size_t)GN * 4, stream);
  hist_kernel<<<1563, 256, 0, stream>>>(dst, cursor, GE);
  scan_kernel<<<1, 256, 0, stream>>>(cursor, rowptr, GN);
  fill_kernel<<<1563, 256, 0, stream>>>(src, dst, cursor, eid, srcs, dsts, GE);

  convert_kernel<<<784, 256, 0, stream>>>(nf_r, nfc, (long)GN * 32, dflag);
  gather_ef<<<6250, 256, 0, stream>>>(ef_r, eid, efc, dflag);
  prep_weights<<<128, 256, 0, stream>>>(d_in[4], d_in[8], d_in[6], d_in[10], d_in[12],
                                        d_in[5], d_in[7], d_in[9], d_in[11], d_in[13],
                                        WeT, WnpT, WnuT, WoN, WoE,
                                        Wac, bec, bac, bnc, bnoc, beoc, dflag);

  for (int iter = 0; iter < 3; ++iter) {
    int kc0 = (iter == 0) ? 4 : 0;
    dim3 npgrid(NODE_BLKS, 2);
    node_proj<<<npgrid, 256, 0, stream>>>(HNF, nfc, WnpT, Wac, Xs, Xd, as_, ad_, kc0, GN);
    if (iter == 0)
      edge_fused<4><<<EDGE_BLKS, 256, 0, stream>>>(HEF, efc, WeT, Wac, bec, bac, srcs, dsts,
                                                   Xs, Xd, as_, ad_, logit);
    else
      edge_fused<0><<<EDGE_BLKS, 256, 0, stream>>>(HEF, efc, WeT, Wac, bec, bac, srcs, dsts,
                                                   Xs, Xd, as_, ad_, logit);
    aggregate<<<(GN + 3) / 4, 256, 0, stream>>>(rowptr, logit, HEF, AGG, GN);
    node_update<<<NODE_BLKS, 256, 0, stream>>>(HNF, nfc, AGG, WnuT, bnc, kc0, GN);
  }

  float* out_nf = (float*)d_out;
  float* out_ef = (float*)d_out + (size_t)GN * 32;
  head_kernel<<<NODE_BLKS, 256, 0, stream>>>(HNF, WoN, bnoc, out_nf, GN, nullptr);
  head_kernel<<<HEAD_EBLKS, 256, 0, stream>>>(HEF, WoE, beoc, out_ef, GE, eid);
}

// Round 5
// 648.136 us; speedup vs baseline: 1.0932x; 1.0119x over previous
//
#include <hip/hip_runtime.h>

// IJGNN attention-MPNN, 3 iterations. fp32 in/out, bf16 internal.
// Edges processed in dst-sorted (CSR) order; edge head scatters back via eid.
// This rev: edge_fused is BARRIER-FREE in the K-loop -- A and B MFMA fragments
// both loaded per-lane directly from global (A tile streams via L1/L2, B is
// L2-hot WeT), ping-pong regs (afp[2][2], bfp[2][4]), no LDS staging, no
// __syncthreads until the epilogue transpose. Waves run as independent
// streams; latency hidden by occupancy instead of serialized by barriers.
// Basket: scan_kernel 1024 threads; gather_ef vectorized 16B; aggregate
// 2-deep prefetch of next edge group.

#define GN 25000
#define GE 400000
#define NODE_BLKS 196    // ceil(GN/128)
#define EDGE_BLKS 6250   // GE/64 exact (edge_fused tiles)
#define HEAD_EBLKS 3125  // GE/128 exact (head_kernel tiles)

typedef unsigned short u16;
typedef __attribute__((ext_vector_type(8))) short bf16x8;
typedef __attribute__((ext_vector_type(4))) float f32x4;

__device__ inline float b2f(u16 v) {
  union { unsigned int u; float f; } x; x.u = ((unsigned int)v) << 16; return x.f;
}
__device__ inline u16 f2b(float f) {
  union { float f; unsigned int u; } x; x.f = f;
  unsigned int u = x.u;
  u += 0x7fffu + ((u >> 16) & 1u);
  return (u16)(u >> 16);
}

// ---------------- dtype probe + convert ----------------
__global__ void detect_dtype(const void* nf, int* flag) {
  if (blockIdx.x == 0 && threadIdx.x == 0) {
    const u16* p = (const u16*)nf;
    int cnt = 0;
    for (int i = 0; i < 512; i += 2) {
      int e = (p[i] >> 7) & 0xFF;
      if (e >= 0x70 && e <= 0x85) cnt++;
    }
    *flag = (cnt < 128) ? 1 : 0;
  }
}

__global__ void convert_kernel(const void* src, u16* dst, long n, const int* flag) {
  int f32 = *flag;
  long i = (long)blockIdx.x * blockDim.x + threadIdx.x;
  long stride = (long)gridDim.x * blockDim.x;
  for (; i < n; i += stride)
    dst[i] = f32 ? f2b(((const float*)src)[i]) : ((const u16*)src)[i];
}

// gather ef rows into dst-sorted order (+convert), 16B per thread
__global__ void gather_ef(const void* ef, const int* eid, u16* efc, const int* flag) {
  int f32 = *flag;
  long idx = (long)blockIdx.x * blockDim.x + threadIdx.x;
  long ntot = (long)GE * 4;  // 8-col groups
  if (idx >= ntot) return;
  long j = idx >> 2;
  int g = (int)(idx & 3) * 8;
  long e = eid[j];
  uint4 out;
  if (f32) {
    const float* pf = (const float*)ef + e * 32 + g;
    float4 a = ((const float4*)pf)[0];
    float4 b = ((const float4*)pf)[1];
    unsigned int* ov = (unsigned int*)&out;
    ov[0] = (unsigned int)f2b(a.x) | ((unsigned int)f2b(a.y) << 16);
    ov[1] = (unsigned int)f2b(a.z) | ((unsigned int)f2b(a.w) << 16);
    ov[2] = (unsigned int)f2b(b.x) | ((unsigned int)f2b(b.y) << 16);
    ov[3] = (unsigned int)f2b(b.z) | ((unsigned int)f2b(b.w) << 16);
  } else {
    out = *(const uint4*)((const u16*)ef + e * 32 + g);
  }
  *(uint4*)(efc + j * 32 + g) = out;
}

// ---------------- weight prep: convert (raw f32/bf16) + transpose, one launch ----------------
__global__ void prep_weights(const void* We, const void* Wn, const void* Wa,
                             const void* Won, const void* Woe,
                             const void* be, const void* ba, const void* bn,
                             const void* bno, const void* beo,
                             u16* WeT, u16* WnpT, u16* WnuT, u16* WoN, u16* WoE,
                             u16* Wac, u16* bec, u16* bac, u16* bnc, u16* bnoc, u16* beoc,
                             const int* flag) {
  int f32 = *flag;
  auto ld = [&](const void* p, long i) -> u16 {
    return f32 ? f2b(((const float*)p)[i]) : ((const u16*)p)[i];
  };
  int tid = blockIdx.x * blockDim.x + threadIdx.x;
  int nt = gridDim.x * blockDim.x;
  for (int i = tid; i < 128 * 160; i += nt) { int n = i / 160, k = i % 160; WeT[i] = ld(We, (long)(320 + k) * 128 + n); }
  for (int i = tid; i < 256 * 160; i += nt) {
    int c = i / 160, k = i % 160;
    WnpT[i] = (c < 128) ? ld(We, (long)k * 128 + c) : ld(We, (long)(160 + k) * 128 + (c - 128));
  }
  for (int i = tid; i < 128 * 288; i += nt) { int c = i / 288, k = i % 288; WnuT[i] = ld(Wn, (long)k * 128 + c); }
  for (int i = tid; i < 32 * 128; i += nt) {
    int c = i / 128, k = i % 128;
    WoN[i] = ld(Won, (long)k * 32 + c);
    WoE[i] = ld(Woe, (long)k * 32 + c);
  }
  for (int i = tid; i < 480; i += nt) Wac[i] = ld(Wa, i);
  for (int i = tid; i < 128; i += nt) { bec[i] = ld(be, i); bnc[i] = ld(bn, i); }
  for (int i = tid; i < 32; i += nt) { bnoc[i] = ld(bno, i); beoc[i] = ld(beo, i); }
  if (tid == 0) bac[0] = ld(ba, 0);
}

// ---------------- CSR build ----------------
__global__ void hist_kernel(const int* dst, int* counts, int n) {
  for (int e = blockIdx.x * blockDim.x + threadIdx.x; e < n; e += gridDim.x * blockDim.x)
    atomicAdd(&counts[dst[e]], 1);
}

__global__ __launch_bounds__(1024) void scan_kernel(int* cursor, int* rowptr, int n) {
  __shared__ int part[1024];
  int t = threadIdx.x;
  int per = (n + 1023) / 1024;
  int lo = t * per;
  int hi = lo + per; if (hi > n) hi = n;
  if (lo > n) lo = n;
  int s = 0;
  for (int i = lo; i < hi; ++i) s += cursor[i];
  part[t] = s;
  __syncthreads();
  for (int off = 1; off < 1024; off <<= 1) {
    int v = (t >= off) ? part[t - off] : 0;
    __syncthreads();
    part[t] += v;
    __syncthreads();
  }
  int run = (t > 0) ? part[t - 1] : 0;
  for (int i = lo; i < hi; ++i) {
    int c = cursor[i];
    cursor[i] = run;
    rowptr[i + 1] = run + c;
    run += c;
  }
  if (t == 0) rowptr[0] = 0;
}

// fill CSR order + gather src/dst meta in the same pass
__global__ void fill_kernel(const int* src, const int* dst, int* cursor, int* eid,
                            int* srcs, int* dsts, int n) {
  for (int e = blockIdx.x * blockDim.x + threadIdx.x; e < n; e += gridDim.x * blockDim.x) {
    int d = dst[e];
    int p = atomicAdd(&cursor[d], 1);
    eid[p] = e;
    srcs[p] = src[e];
    dsts[p] = d;
  }
}

// ---------------- node projections (MFMA): Xs/Xd [N,128] bf16, as/ad [N] fp32 ----------------
__global__ __launch_bounds__(256)
void node_proj(const u16* HNF, const u16* nf, const u16* WnpT, const u16* W_attn,
               u16* Xs, u16* Xd, float* as_, float* ad_, int kc0, int nrows) {
  __shared__ union {
    struct { __align__(16) u16 A[128][40]; __align__(16) u16 B[128][40]; } st;
    u16 C[128][130];  // bf16 transpose buffer (final values; no extra rounding)
  } sm;
  __shared__ float dotbuf[128][2];
  int sel = blockIdx.y, blk = blockIdx.x, tid = threadIdx.x;
  int lane = tid & 63, wv = tid >> 6, wr = wv & 1, wc = wv >> 1;
  const u16* BT = WnpT + sel * 128 * 160;
  u16* OUT = sel ? Xd : Xs;
  float* AOUT = sel ? ad_ : as_;
  const u16* wa = W_attn + sel * 160;
  f32x4 acc[4][4];
  f32x4 zf = {0.f, 0.f, 0.f, 0.f};
  for (int i = 0; i < 4; ++i) for (int j = 0; j < 4; ++j) acc[i][j] = zf;
  float dp = 0.f;
  int arow = tid >> 1, ahalf = (tid & 1) * 16;
  int r0 = blk * 128;
  for (int kc = kc0; kc < 5; ++kc) {
    {
      int r = r0 + arow;
      uint4 v0 = make_uint4(0, 0, 0, 0), v1 = make_uint4(0, 0, 0, 0);
      if (r < nrows) {
        const uint4* p = (kc < 4) ? (const uint4*)(HNF + (size_t)r * 128 + kc * 32 + ahalf)
                                  : (const uint4*)(nf + (size_t)r * 32 + ahalf);
        v0 = p[0]; v1 = p[1];
      }
      *(uint4*)&sm.st.A[arow][ahalf] = v0;
      *(uint4*)&sm.st.A[arow][ahalf + 8] = v1;
    }
    {
      const uint4* p = (const uint4*)(BT + arow * 160 + kc * 32 + ahalf);
      uint4 v0 = p[0], v1 = p[1];
      *(uint4*)&sm.st.B[arow][ahalf] = v0;
      *(uint4*)&sm.st.B[arow][ahalf + 8] = v1;
    }
    __syncthreads();
    {
      float s = 0.f;
      for (int j = 0; j < 16; ++j) s += b2f(sm.st.A[arow][ahalf + j]) * b2f(wa[kc * 32 + ahalf + j]);
      dp += s;
    }
    int q = lane >> 4, l16 = lane & 15;
    bf16x8 af[4], bfr[4];
    for (int i = 0; i < 4; ++i) af[i] = *(const bf16x8*)&sm.st.A[wr * 64 + i * 16 + l16][q * 8];
    for (int j = 0; j < 4; ++j) bfr[j] = *(const bf16x8*)&sm.st.B[wc * 64 + j * 16 + l16][q * 8];
    for (int i = 0; i < 4; ++i)
      for (int j = 0; j < 4; ++j)
        acc[i][j] = __builtin_amdgcn_mfma_f32_16x16x32_bf16(af[i], bfr[j], acc[i][j], 0, 0, 0);
    __syncthreads();
  }
  dotbuf[arow][tid & 1] = dp;
  // scatter acc -> LDS transpose buffer (overlays staging; K-loop is done)
  {
    int q = lane >> 4, l16 = lane & 15;
    for (int i = 0; i < 4; ++i)
      for (int j = 0; j < 4; ++j) {
        int col = wc * 64 + j * 16 + l16;
        for (int rr = 0; rr < 4; ++rr) {
          int row = wr * 64 + i * 16 + q * 4 + rr;
          sm.C[row][col] = f2b(acc[i][j][rr]);
        }
      }
  }
  __syncthreads();
  if (tid < 128) {
    int r = r0 + tid;
    if (r < nrows) AOUT[r] = dotbuf[tid][0] + dotbuf[tid][1];
  }
  // vectorized store: each thread owns one row-half (64 cols = 8x dwordx4)
  {
    int r = tid >> 1, h = (tid & 1) * 64;
    int rg = r0 + r;
    if (rg < nrows) {
      uint4* po = (uint4*)(OUT + (size_t)rg * 128 + h);
      for (int k = 0; k < 8; ++k) {
        unsigned int a0 = *(const unsigned int*)&sm.C[r][h + k * 8];
        unsigned int a1 = *(const unsigned int*)&sm.C[r][h + k * 8 + 2];
        unsigned int a2 = *(const unsigned int*)&sm.C[r][h + k * 8 + 4];
        unsigned int a3 = *(const unsigned int*)&sm.C[r][h + k * 8 + 6];
        po[k] = make_uint4(a0, a1, a2, a3);
      }
    }
  }
}

// ---------------- edge stage: barrier-free K-loop, all frags direct from global ----------------
// Per wave per chunk: 2 A-frag loads (16B/lane, per-lane addr into the tile's
// contiguous 20KB region -> L1/L2) + 4 B-frag loads (L2-hot WeT) + 8 MFMA.
// Ping-pong regs, no LDS, no barriers until the epilogue transpose.
template <int KC0>
__global__ __launch_bounds__(256, 4)
void edge_fused(u16* HEF, const u16* ef, const u16* WeT, const u16* W_attn,
                const u16* b_edge, const u16* b_attn, const int* srcs, const int* dsts,
                const u16* Xs, const u16* Xd, const float* as_, const float* ad_,
                float* logit) {
  __shared__ float C[64][65];  // epilogue transpose; stride 65 -> bank spread
  __shared__ float dotbuf[64];
  int blk = blockIdx.x, tid = threadIdx.x;
  int lane = tid & 63, wv = tid >> 6, wr = wv & 1, wc = wv >> 1;
  int q = lane >> 4, l16 = lane & 15;
  f32x4 acc[2][4];
  f32x4 zf = {0.f, 0.f, 0.f, 0.f};
  for (int i = 0; i < 2; ++i) for (int j = 0; j < 4; ++j) acc[i][j] = zf;
  float dp[2] = {0.f, 0.f};
  long e0 = (long)blk * 64;
  const u16* wa = W_attn + 320;
  // A fragment rows for this wave (2 frags: rows ar, ar+16)
  long ar = e0 + wr * 32 + l16;
  const u16* aH0 = HEF + ar * 128 + q * 8;          // + kc*32 for kc<4
  const u16* aH1 = aH0 + 16 * 128;
  const u16* aE0 = ef + ar * 32 + q * 8;            // kc==4
  const u16* aE1 = aE0 + 16 * 32;
  // B fragment rows (4 frags)
  const u16* bW = WeT + (size_t)(wc * 64 + l16) * 160 + q * 8;  // + j*16*160 + kc*32

  bf16x8 afp[2][2], bfp[2][4];
#pragma unroll
  for (int j = 0; j < 4; ++j)
    bfp[KC0 & 1][j] = *(const bf16x8*)(bW + (size_t)j * 16 * 160 + KC0 * 32);
  afp[KC0 & 1][0] = (KC0 < 4) ? *(const bf16x8*)(aH0 + KC0 * 32) : *(const bf16x8*)aE0;
  afp[KC0 & 1][1] = (KC0 < 4) ? *(const bf16x8*)(aH1 + KC0 * 32) : *(const bf16x8*)aE1;

#pragma unroll
  for (int kc = KC0; kc < 5; ++kc) {
    int cur = kc & 1, nxt = cur ^ 1;
    if (kc < 4) {  // issue next-chunk loads; hide under MFMA + attn dot
      int kn = kc + 1;
      afp[nxt][0] = (kn < 4) ? *(const bf16x8*)(aH0 + kn * 32) : *(const bf16x8*)aE0;
      afp[nxt][1] = (kn < 4) ? *(const bf16x8*)(aH1 + kn * 32) : *(const bf16x8*)aE1;
#pragma unroll
      for (int j = 0; j < 4; ++j)
        bfp[nxt][j] = *(const bf16x8*)(bW + (size_t)j * 16 * 160 + kn * 32);
    }
    if (wc == 0) {
      bf16x8 wv8 = *(const bf16x8*)&wa[kc * 32 + q * 8];
      float wf[8];
      for (int j = 0; j < 8; ++j) wf[j] = b2f((u16)wv8[j]);
      for (int i = 0; i < 2; ++i)
        for (int j = 0; j < 8; ++j) dp[i] += b2f((u16)afp[cur][i][j]) * wf[j];
    }
    for (int i = 0; i < 2; ++i)
      for (int j = 0; j < 4; ++j)
        acc[i][j] = __builtin_amdgcn_mfma_f32_16x16x32_bf16(afp[cur][i], bfp[cur][j], acc[i][j], 0, 0, 0);
  }
  if (wc == 0) {
    for (int i = 0; i < 2; ++i) {
      dp[i] += __shfl_xor(dp[i], 16);
      dp[i] += __shfl_xor(dp[i], 32);
    }
    if (q == 0)
      for (int i = 0; i < 2; ++i) dotbuf[wr * 32 + i * 16 + l16] = dp[i];
  }
  int r = tid >> 2, qh = tid & 3;  // each thread: one edge row, 16 cols/pass
  long e = e0 + r;
  int s = srcs[e], d = dsts[e];
#pragma unroll
  for (int p = 0; p < 2; ++p) {
    int cb = p * 64 + qh * 16;
    // issue vector gathers early: latency hides under barrier + LDS scatter
    const uint4* ps = (const uint4*)(Xs + (size_t)s * 128 + cb);
    const uint4* pd = (const uint4*)(Xd + (size_t)d * 128 + cb);
    uint4 gs0 = ps[0], gs1 = ps[1], gd0 = pd[0], gd1 = pd[1];
    // p=0: orders dotbuf writes before reads; p=1: protects C from pass-0 readers
    __syncthreads();
    if (wc == p) {  // this wave pair's acc covers cols [p*64, p*64+64)
      for (int i = 0; i < 2; ++i)
        for (int j = 0; j < 4; ++j) {
          int col = j * 16 + l16;
          float bb = b2f(b_edge[p * 64 + col]);
          for (int rr = 0; rr < 4; ++rr)
            C[wr * 32 + i * 16 + q * 4 + rr][col] = acc[i][j][rr] + bb;
        }
    }
    __syncthreads();
    if (p == 0 && tid < 64) {
      long ee = e0 + tid;
      logit[ee] = dotbuf[tid] + as_[srcs[ee]] + ad_[dsts[ee]] + b2f(b_attn[0]);
    }
    unsigned int us[8], ud[8];
    *(uint4*)&us[0] = gs0; *(uint4*)&us[4] = gs1;
    *(uint4*)&ud[0] = gd0; *(uint4*)&ud[4] = gd1;
    unsigned int ov[8];
    for (int w = 0; w < 8; ++w) {
      float c0 = C[r][qh * 16 + 2 * w];
      float c1 = C[r][qh * 16 + 2 * w + 1];
      float v0 = c0 + b2f((u16)(us[w] & 0xffffu)) + b2f((u16)(ud[w] & 0xffffu));
      float v1 = c1 + b2f((u16)(us[w] >> 16)) + b2f((u16)(ud[w] >> 16));
      ov[w] = (unsigned int)f2b(fmaxf(v0, 0.f)) | ((unsigned int)f2b(fmaxf(v1, 0.f)) << 16);
    }
    uint4* po = (uint4*)(HEF + e * 128 + cb);
    po[0] = *(uint4*)&ov[0];
    po[1] = *(uint4*)&ov[4];
  }
}

// ---------------- per-dst softmax + aggregation ----------------
// 1 wave per dst row; 8 edges/iteration with 2-deep software prefetch of the
// next group: lane = (edge-slot sub, col-group cl), 32B/lane M reads,
// 3-level shfl_xor fold over the 8 edge-slots.
__global__ __launch_bounds__(256)
void aggregate(const int* rowptr, const float* logit, const u16* M, u16* AGG, int nrows) {
  int gw = (blockIdx.x * blockDim.x + threadIdx.x) >> 6;
  int lane = threadIdx.x & 63;
  if (gw >= nrows) return;
  int beg = rowptr[gw], end = rowptr[gw + 1];
  int sub = lane >> 3, cl = lane & 7;
  float mx = -1e30f;
  for (int j = beg + lane; j < end; j += 64) mx = fmaxf(mx, logit[j]);
  for (int off = 32; off > 0; off >>= 1) mx = fmaxf(mx, __shfl_xor(mx, off));
  float acc[16];
  for (int t = 0; t < 16; ++t) acc[t] = 0.f;
  float denom = 0.f;
  // preload first group
  float wc = 0.f;
  uint4 m0c = make_uint4(0, 0, 0, 0), m1c = make_uint4(0, 0, 0, 0);
  {
    int j = beg + sub;
    if (j < end) {
      wc = __expf(logit[j] - mx);
      const uint4* mp = (const uint4*)(M + (size_t)j * 128 + cl * 16);
      m0c = mp[0]; m1c = mp[1];
    }
  }
  for (int j0 = beg; j0 < end; j0 += 8) {
    // issue next-group loads before consuming current (hides L2/L3 latency)
    float wn = 0.f;
    uint4 m0n = make_uint4(0, 0, 0, 0), m1n = make_uint4(0, 0, 0, 0);
    int jn = j0 + 8 + sub;
    if (jn < end) {
      wn = __expf(logit[jn] - mx);
      const uint4* mp = (const uint4*)(M + (size_t)jn * 128 + cl * 16);
      m0n = mp[0]; m1n = mp[1];
    }
    denom += wc;
    const unsigned int* mw0 = (const unsigned int*)&m0c;
    const unsigned int* mw1 = (const unsigned int*)&m1c;
    for (int t = 0; t < 4; ++t) {
      acc[2 * t]     += wc * b2f((u16)(mw0[t] & 0xffffu));
      acc[2 * t + 1] += wc * b2f((u16)(mw0[t] >> 16));
      acc[8 + 2 * t]     += wc * b2f((u16)(mw1[t] & 0xffffu));
      acc[8 + 2 * t + 1] += wc * b2f((u16)(mw1[t] >> 16));
    }
    wc = wn; m0c = m0n; m1c = m1n;
  }
  denom += __shfl_xor(denom, 8);
  denom += __shfl_xor(denom, 16);
  denom += __shfl_xor(denom, 32);
  for (int t = 0; t < 16; ++t) {
    acc[t] += __shfl_xor(acc[t], 8);
    acc[t] += __shfl_xor(acc[t], 16);
    acc[t] += __shfl_xor(acc[t], 32);
  }
  float inv = 1.0f / fmaxf(denom, 1e-16f);
  if (sub == 0) {
    unsigned int ov[8];
    for (int t = 0; t < 8; ++t)
      ov[t] = (unsigned int)f2b(acc[2 * t] * inv) | ((unsigned int)f2b(acc[2 * t + 1] * inv) << 16);
    uint4* po = (uint4*)(AGG + (size_t)gw * 128 + cl * 16);
    po[0] = *(uint4*)&ov[0];
    po[1] = *(uint4*)&ov[4];
  }
}

// ---------------- node update (MFMA, in-place HNF) ----------------
__global__ __launch_bounds__(256)
void node_update(u16* HNF, const u16* nf, const u16* AGG, const u16* WnuT,
                 const u16* b_node, int kc0, int nrows) {
  __shared__ union {
    struct { __align__(16) u16 A[128][40]; __align__(16) u16 B[128][40]; } st;
    u16 C[128][130];
  } sm;
  int blk = blockIdx.x, tid = threadIdx.x;
  int lane = tid & 63, wv = tid >> 6, wr = wv & 1, wc = wv >> 1;
  f32x4 acc[4][4];
  f32x4 zf = {0.f, 0.f, 0.f, 0.f};
  for (int i = 0; i < 4; ++i) for (int j = 0; j < 4; ++j) acc[i][j] = zf;
  int arow = tid >> 1, ahalf = (tid & 1) * 16;
  int r0 = blk * 128;
  for (int kc = kc0; kc < 9; ++kc) {
    {
      int r = r0 + arow;
      uint4 v0 = make_uint4(0, 0, 0, 0), v1 = make_uint4(0, 0, 0, 0);
      if (r < nrows) {
        const u16* p;
        if (kc < 4) p = HNF + (size_t)r * 128 + kc * 32 + ahalf;
        else if (kc == 4) p = nf + (size_t)r * 32 + ahalf;
        else p = AGG + (size_t)r * 128 + (kc - 5) * 32 + ahalf;
        v0 = ((const uint4*)p)[0];
        v1 = ((const uint4*)p)[1];
      }
      *(uint4*)&sm.st.A[arow][ahalf] = v0;
      *(uint4*)&sm.st.A[arow][ahalf + 8] = v1;
    }
    {
      const uint4* p = (const uint4*)(WnuT + arow * 288 + kc * 32 + ahalf);
      uint4 v0 = p[0], v1 = p[1];
      *(uint4*)&sm.st.B[arow][ahalf] = v0;
      *(uint4*)&sm.st.B[arow][ahalf + 8] = v1;
    }
    __syncthreads();
    int q = lane >> 4, l16 = lane & 15;
    bf16x8 af[4], bfr[4];
    for (int i = 0; i < 4; ++i) af[i] = *(const bf16x8*)&sm.st.A[wr * 64 + i * 16 + l16][q * 8];
    for (int j = 0; j < 4; ++j) bfr[j] = *(const bf16x8*)&sm.st.B[wc * 64 + j * 16 + l16][q * 8];
    for (int i = 0; i < 4; ++i)
      for (int j = 0; j < 4; ++j)
        acc[i][j] = __builtin_amdgcn_mfma_f32_16x16x32_bf16(af[i], bfr[j], acc[i][j], 0, 0, 0);
    __syncthreads();
  }
  int q = lane >> 4, l16 = lane & 15;
  for (int i = 0; i < 4; ++i)
    for (int j = 0; j < 4; ++j) {
      int col = wc * 64 + j * 16 + l16;
      float bb = b2f(b_node[col]);
      for (int rr = 0; rr < 4; ++rr) {
        int row = wr * 64 + i * 16 + q * 4 + rr;
        sm.C[row][col] = f2b(fmaxf(acc[i][j][rr] + bb, 0.f));
      }
    }
  __syncthreads();
  {
    int r = tid >> 1, h = (tid & 1) * 64;
    int rg = r0 + r;
    if (rg < nrows) {
      uint4* po = (uint4*)(HNF + (size_t)rg * 128 + h);
      for (int k = 0; k < 8; ++k) {
        unsigned int a0 = *(const unsigned int*)&sm.C[r][h + k * 8];
        unsigned int a1 = *(const unsigned int*)&sm.C[r][h + k * 8 + 2];
        unsigned int a2 = *(const unsigned int*)&sm.C[r][h + k * 8 + 4];
        unsigned int a3 = *(const unsigned int*)&sm.C[r][h + k * 8 + 6];
        po[k] = make_uint4(a0, a1, a2, a3);
      }
    }
  }
}

// ---------------- output heads (MFMA, fp32 output, optional row remap) ----------------
__global__ __launch_bounds__(256)
void head_kernel(const u16* IN, const u16* WT, const u16* bias, float* OUT, long R,
                 const int* remap) {
  __shared__ __align__(16) u16 Asm[128][40];
  __shared__ __align__(16) u16 Bsm[32][40];
  int blk = blockIdx.x, tid = threadIdx.x;
  int lane = tid & 63, wv = tid >> 6;
  f32x4 acc[2][2];
  f32x4 zf = {0.f, 0.f, 0.f, 0.f};
  for (int i = 0; i < 2; ++i) for (int j = 0; j < 2; ++j) acc[i][j] = zf;
  int arow = tid >> 1, ahalf = (tid & 1) * 16;
  long r0 = (long)blk * 128;
  for (int kc = 0; kc < 4; ++kc) {
    {
      long r = r0 + arow;
      uint4 v0 = make_uint4(0, 0, 0, 0), v1 = make_uint4(0, 0, 0, 0);
      if (r < R) {
        const uint4* p = (const uint4*)(IN + r * 128 + kc * 32 + ahalf);
        v0 = p[0]; v1 = p[1];
      }
      *(uint4*)&Asm[arow][ahalf] = v0;
      *(uint4*)&Asm[arow][ahalf + 8] = v1;
    }
    if (tid < 64) {
      const uint4* p = (const uint4*)(WT + arow * 128 + kc * 32 + ahalf);
      uint4 v0 = p[0], v1 = p[1];
      *(uint4*)&Bsm[arow][ahalf] = v0;
      *(uint4*)&Bsm[arow][ahalf + 8] = v1;
    }
    __syncthreads();
    int q = lane >> 4, l16 = lane & 15;
    bf16x8 af[2], bfr[2];
    for (int i = 0; i < 2; ++i) af[i] = *(const bf16x8*)&Asm[wv * 32 + i * 16 + l16][q * 8];
    for (int j = 0; j < 2; ++j) bfr[j] = *(const bf16x8*)&Bsm[j * 16 + l16][q * 8];
    for (int i = 0; i < 2; ++i)
      for (int j = 0; j < 2; ++j)
        acc[i][j] = __builtin_amdgcn_mfma_f32_16x16x32_bf16(af[i], bfr[j], acc[i][j], 0, 0, 0);
    __syncthreads();
  }
  int q = lane >> 4, l16 = lane & 15;
  for (int i = 0; i < 2; ++i)
    for (int rr = 0; rr < 4; ++rr) {
      long r = r0 + wv * 32 + i * 16 + q * 4 + rr;
      if (r < R) {
        long ro = remap ? (long)remap[r] : r;
        for (int j = 0; j < 2; ++j) {
          int col = j * 16 + l16;
          OUT[ro * 32 + col] = acc[i][j][rr] + b2f(bias[col]);
        }
      }
    }
}

extern "C" void kernel_launch(void* const* d_in, const int* in_sizes, int n_in,
                              void* d_out, int out_size, void* d_ws, size_t ws_size,
                              hipStream_t stream) {
  const size_t REQUIRED = 160000000;
  if (ws_size < REQUIRED) return;

  const void* nf_r = d_in[0];
  const void* ef_r = d_in[1];
  const int* src = (const int*)d_in[2];
  const int* dst = (const int*)d_in[3];

  char* ws = (char*)d_ws;
  auto alloc = [&](size_t bytes) {
    char* p = ws;
    ws += (bytes + 255) & ~(size_t)255;
    return p;
  };
  u16* HEF = (u16*)alloc((size_t)GE * 128 * 2);
  u16* HNF = (u16*)alloc((size_t)GN * 128 * 2);
  u16* Xs = (u16*)alloc((size_t)GN * 128 * 2);
  u16* Xd = (u16*)alloc((size_t)GN * 128 * 2);
  float* as_ = (float*)alloc((size_t)GN * 4);
  float* ad_ = (float*)alloc((size_t)GN * 4);
  float* logit = (float*)alloc((size_t)GE * 4);
  int* rowptr = (int*)alloc((size_t)(GN + 1) * 4);
  int* cursor = (int*)alloc((size_t)GN * 4);
  int* eid = (int*)alloc((size_t)GE * 4);
  int* srcs = (int*)alloc((size_t)GE * 4);
  int* dsts = (int*)alloc((size_t)GE * 4);
  u16* WeT = (u16*)alloc(128 * 160 * 2);
  u16* WnpT = (u16*)alloc(256 * 160 * 2);
  u16* WnuT = (u16*)alloc(128 * 288 * 2);
  u16* WoN = (u16*)alloc(32 * 128 * 2);
  u16* WoE = (u16*)alloc(32 * 128 * 2);
  u16* nfc = (u16*)alloc((size_t)GN * 32 * 2);
  u16* efc = (u16*)alloc((size_t)GE * 32 * 2);
  u16* bec = (u16*)alloc(128 * 2);
  u16* Wac = (u16*)alloc(480 * 2);
  u16* bac = (u16*)alloc(2);
  u16* bnc = (u16*)alloc(128 * 2);
  u16* bnoc = (u16*)alloc(32 * 2);
  u16* beoc = (u16*)alloc(32 * 2);
  int* dflag = (int*)alloc(4);
  u16* AGG = Xs;  // overlay: Xs (bf16, 6.4MB) dead after edge stage; AGG consumed
                  // by node_update before next iter's node_proj rewrites Xs

  detect_dtype<<<1, 64, 0, stream>>>(nf_r, dflag);
  // CSR build first (gathers depend on eid)
  hipMemsetAsync(cursor, 0, (size_t)GN * 4, stream);
  hist_kernel<<<1563, 256, 0, stream>>>(dst, cursor, GE);
  scan_kernel<<<1, 1024, 0, stream>>>(cursor, rowptr, GN);
  fill_kernel<<<1563, 256, 0, stream>>>(src, dst, cursor, eid, srcs, dsts, GE);

  convert_kernel<<<784, 256, 0, stream>>>(nf_r, nfc, (long)GN * 32, dflag);
  gather_ef<<<6250, 256, 0, stream>>>(ef_r, eid, efc, dflag);
  prep_weights<<<128, 256, 0, stream>>>(d_in[4], d_in[8], d_in[6], d_in[10], d_in[12],
                                        d_in[5], d_in[7], d_in[9], d_in[11], d_in[13],
                                        WeT, WnpT, WnuT, WoN, WoE,
                                        Wac, bec, bac, bnc, bnoc, beoc, dflag);

  for (int iter = 0; iter < 3; ++iter) {
    int kc0 = (iter == 0) ? 4 : 0;
    dim3 npgrid(NODE_BLKS, 2);
    node_proj<<<npgrid, 256, 0, stream>>>(HNF, nfc, WnpT, Wac, Xs, Xd, as_, ad_, kc0, GN);
    if (iter == 0)
      edge_fused<4><<<EDGE_BLKS, 256, 0, stream>>>(HEF, efc, WeT, Wac, bec, bac, srcs, dsts,
                                                   Xs, Xd, as_, ad_, logit);
    else
      edge_fused<0><<<EDGE_BLKS, 256, 0, stream>>>(HEF, efc, WeT, Wac, bec, bac, srcs, dsts,
                                                   Xs, Xd, as_, ad_, logit);
    aggregate<<<(GN + 3) / 4, 256, 0, stream>>>(rowptr, logit, HEF, AGG, GN);
    node_update<<<NODE_BLKS, 256, 0, stream>>>(HNF, nfc, AGG, WnuT, bnc, kc0, GN);
  }

  float* out_nf = (float*)d_out;
  float* out_ef = (float*)d_out + (size_t)GN * 32;
  head_kernel<<<NODE_BLKS, 256, 0, stream>>>(HNF, WoN, bnoc, out_nf, GN, nullptr);
  head_kernel<<<HEAD_EBLKS, 256, 0, stream>>>(HEF, WoE, beoc, out_ef, GE, eid);
}

// Round 6
// 603.613 us; speedup vs baseline: 1.1738x; 1.0738x over previous
//
#include <hip/hip_runtime.h>

// IJGNN attention-MPNN, 3 iterations. fp32 in/out, bf16 internal.
// Edges processed in dst-sorted (CSR) order; edge head scatters back via eid.
// This rev: edge_fused reverted to the round-4 body (best measured: 74us, clean
// traffic; barrier-free round-5 variant regressed to 90us on scattered A reads).
// The proven 1-deep register-prefetch transform (overlap chunk kc+1 global
// loads with chunk kc MFMA) is applied to node_proj, node_update, head_kernel.
// Basket kept: scan 1024 threads, vectorized gather_ef, aggregate prefetch.

#define GN 25000
#define GE 400000
#define NODE_BLKS 196    // ceil(GN/128)
#define EDGE_BLKS 6250   // GE/64 exact (edge_fused tiles)
#define HEAD_EBLKS 3125  // GE/128 exact (head_kernel tiles)

typedef unsigned short u16;
typedef __attribute__((ext_vector_type(8))) short bf16x8;
typedef __attribute__((ext_vector_type(4))) float f32x4;

__device__ inline float b2f(u16 v) {
  union { unsigned int u; float f; } x; x.u = ((unsigned int)v) << 16; return x.f;
}
__device__ inline u16 f2b(float f) {
  union { float f; unsigned int u; } x; x.f = f;
  unsigned int u = x.u;
  u += 0x7fffu + ((u >> 16) & 1u);
  return (u16)(u >> 16);
}

// ---------------- dtype probe + convert ----------------
__global__ void detect_dtype(const void* nf, int* flag) {
  if (blockIdx.x == 0 && threadIdx.x == 0) {
    const u16* p = (const u16*)nf;
    int cnt = 0;
    for (int i = 0; i < 512; i += 2) {
      int e = (p[i] >> 7) & 0xFF;
      if (e >= 0x70 && e <= 0x85) cnt++;
    }
    *flag = (cnt < 128) ? 1 : 0;
  }
}

__global__ void convert_kernel(const void* src, u16* dst, long n, const int* flag) {
  int f32 = *flag;
  long i = (long)blockIdx.x * blockDim.x + threadIdx.x;
  long stride = (long)gridDim.x * blockDim.x;
  for (; i < n; i += stride)
    dst[i] = f32 ? f2b(((const float*)src)[i]) : ((const u16*)src)[i];
}

// gather ef rows into dst-sorted order (+convert), 16B per thread
__global__ void gather_ef(const void* ef, const int* eid, u16* efc, const int* flag) {
  int f32 = *flag;
  long idx = (long)blockIdx.x * blockDim.x + threadIdx.x;
  long ntot = (long)GE * 4;  // 8-col groups
  if (idx >= ntot) return;
  long j = idx >> 2;
  int g = (int)(idx & 3) * 8;
  long e = eid[j];
  uint4 out;
  if (f32) {
    const float* pf = (const float*)ef + e * 32 + g;
    float4 a = ((const float4*)pf)[0];
    float4 b = ((const float4*)pf)[1];
    unsigned int* ov = (unsigned int*)&out;
    ov[0] = (unsigned int)f2b(a.x) | ((unsigned int)f2b(a.y) << 16);
    ov[1] = (unsigned int)f2b(a.z) | ((unsigned int)f2b(a.w) << 16);
    ov[2] = (unsigned int)f2b(b.x) | ((unsigned int)f2b(b.y) << 16);
    ov[3] = (unsigned int)f2b(b.z) | ((unsigned int)f2b(b.w) << 16);
  } else {
    out = *(const uint4*)((const u16*)ef + e * 32 + g);
  }
  *(uint4*)(efc + j * 32 + g) = out;
}

// ---------------- weight prep: convert (raw f32/bf16) + transpose, one launch ----------------
__global__ void prep_weights(const void* We, const void* Wn, const void* Wa,
                             const void* Won, const void* Woe,
                             const void* be, const void* ba, const void* bn,
                             const void* bno, const void* beo,
                             u16* WeT, u16* WnpT, u16* WnuT, u16* WoN, u16* WoE,
                             u16* Wac, u16* bec, u16* bac, u16* bnc, u16* bnoc, u16* beoc,
                             const int* flag) {
  int f32 = *flag;
  auto ld = [&](const void* p, long i) -> u16 {
    return f32 ? f2b(((const float*)p)[i]) : ((const u16*)p)[i];
  };
  int tid = blockIdx.x * blockDim.x + threadIdx.x;
  int nt = gridDim.x * blockDim.x;
  for (int i = tid; i < 128 * 160; i += nt) { int n = i / 160, k = i % 160; WeT[i] = ld(We, (long)(320 + k) * 128 + n); }
  for (int i = tid; i < 256 * 160; i += nt) {
    int c = i / 160, k = i % 160;
    WnpT[i] = (c < 128) ? ld(We, (long)k * 128 + c) : ld(We, (long)(160 + k) * 128 + (c - 128));
  }
  for (int i = tid; i < 128 * 288; i += nt) { int c = i / 288, k = i % 288; WnuT[i] = ld(Wn, (long)k * 128 + c); }
  for (int i = tid; i < 32 * 128; i += nt) {
    int c = i / 128, k = i % 128;
    WoN[i] = ld(Won, (long)k * 32 + c);
    WoE[i] = ld(Woe, (long)k * 32 + c);
  }
  for (int i = tid; i < 480; i += nt) Wac[i] = ld(Wa, i);
  for (int i = tid; i < 128; i += nt) { bec[i] = ld(be, i); bnc[i] = ld(bn, i); }
  for (int i = tid; i < 32; i += nt) { bnoc[i] = ld(bno, i); beoc[i] = ld(beo, i); }
  if (tid == 0) bac[0] = ld(ba, 0);
}

// ---------------- CSR build ----------------
__global__ void hist_kernel(const int* dst, int* counts, int n) {
  for (int e = blockIdx.x * blockDim.x + threadIdx.x; e < n; e += gridDim.x * blockDim.x)
    atomicAdd(&counts[dst[e]], 1);
}

__global__ __launch_bounds__(1024) void scan_kernel(int* cursor, int* rowptr, int n) {
  __shared__ int part[1024];
  int t = threadIdx.x;
  int per = (n + 1023) / 1024;
  int lo = t * per;
  int hi = lo + per; if (hi > n) hi = n;
  if (lo > n) lo = n;
  int s = 0;
  for (int i = lo; i < hi; ++i) s += cursor[i];
  part[t] = s;
  __syncthreads();
  for (int off = 1; off < 1024; off <<= 1) {
    int v = (t >= off) ? part[t - off] : 0;
    __syncthreads();
    part[t] += v;
    __syncthreads();
  }
  int run = (t > 0) ? part[t - 1] : 0;
  for (int i = lo; i < hi; ++i) {
    int c = cursor[i];
    cursor[i] = run;
    rowptr[i + 1] = run + c;
    run += c;
  }
  if (t == 0) rowptr[0] = 0;
}

// fill CSR order + gather src/dst meta in the same pass
__global__ void fill_kernel(const int* src, const int* dst, int* cursor, int* eid,
                            int* srcs, int* dsts, int n) {
  for (int e = blockIdx.x * blockDim.x + threadIdx.x; e < n; e += gridDim.x * blockDim.x) {
    int d = dst[e];
    int p = atomicAdd(&cursor[d], 1);
    eid[p] = e;
    srcs[p] = src[e];
    dsts[p] = d;
  }
}

// ---------------- node projections (MFMA): Xs/Xd [N,128] bf16, as/ad [N] fp32 ----------------
// 1-deep reg prefetch: chunk kc+1 global loads issued after chunk kc's LDS
// write; latency hides under the dot + MFMA phase.
__global__ __launch_bounds__(256)
void node_proj(const u16* HNF, const u16* nf, const u16* WnpT, const u16* W_attn,
               u16* Xs, u16* Xd, float* as_, float* ad_, int kc0, int nrows) {
  __shared__ union {
    struct { __align__(16) u16 A[128][40]; __align__(16) u16 B[128][40]; } st;
    u16 C[128][130];  // bf16 transpose buffer (final values; no extra rounding)
  } sm;
  __shared__ float dotbuf[128][2];
  int sel = blockIdx.y, blk = blockIdx.x, tid = threadIdx.x;
  int lane = tid & 63, wv = tid >> 6, wr = wv & 1, wc = wv >> 1;
  const u16* BT = WnpT + sel * 128 * 160;
  u16* OUT = sel ? Xd : Xs;
  float* AOUT = sel ? ad_ : as_;
  const u16* wa = W_attn + sel * 160;
  f32x4 acc[4][4];
  f32x4 zf = {0.f, 0.f, 0.f, 0.f};
  for (int i = 0; i < 4; ++i) for (int j = 0; j < 4; ++j) acc[i][j] = zf;
  float dp = 0.f;
  int arow = tid >> 1, ahalf = (tid & 1) * 16;
  int r0 = blk * 128;
  int ra = r0 + arow;
  uint4 va0 = make_uint4(0, 0, 0, 0), va1 = make_uint4(0, 0, 0, 0), vb0, vb1;
  {
    if (ra < nrows) {
      const uint4* p = (kc0 < 4) ? (const uint4*)(HNF + (size_t)ra * 128 + kc0 * 32 + ahalf)
                                 : (const uint4*)(nf + (size_t)ra * 32 + ahalf);
      va0 = p[0]; va1 = p[1];
    }
    const uint4* pb = (const uint4*)(BT + arow * 160 + kc0 * 32 + ahalf);
    vb0 = pb[0]; vb1 = pb[1];
  }
  for (int kc = kc0; kc < 5; ++kc) {
    *(uint4*)&sm.st.A[arow][ahalf] = va0;
    *(uint4*)&sm.st.A[arow][ahalf + 8] = va1;
    *(uint4*)&sm.st.B[arow][ahalf] = vb0;
    *(uint4*)&sm.st.B[arow][ahalf + 8] = vb1;
    if (kc < 4) {  // prefetch next chunk
      int kn = kc + 1;
      va0 = make_uint4(0, 0, 0, 0); va1 = make_uint4(0, 0, 0, 0);
      if (ra < nrows) {
        const uint4* p = (kn < 4) ? (const uint4*)(HNF + (size_t)ra * 128 + kn * 32 + ahalf)
                                  : (const uint4*)(nf + (size_t)ra * 32 + ahalf);
        va0 = p[0]; va1 = p[1];
      }
      const uint4* pb = (const uint4*)(BT + arow * 160 + kn * 32 + ahalf);
      vb0 = pb[0]; vb1 = pb[1];
    }
    __syncthreads();
    {
      float s = 0.f;
      for (int j = 0; j < 16; ++j) s += b2f(sm.st.A[arow][ahalf + j]) * b2f(wa[kc * 32 + ahalf + j]);
      dp += s;
    }
    int q = lane >> 4, l16 = lane & 15;
    bf16x8 af[4], bfr[4];
    for (int i = 0; i < 4; ++i) af[i] = *(const bf16x8*)&sm.st.A[wr * 64 + i * 16 + l16][q * 8];
    for (int j = 0; j < 4; ++j) bfr[j] = *(const bf16x8*)&sm.st.B[wc * 64 + j * 16 + l16][q * 8];
    for (int i = 0; i < 4; ++i)
      for (int j = 0; j < 4; ++j)
        acc[i][j] = __builtin_amdgcn_mfma_f32_16x16x32_bf16(af[i], bfr[j], acc[i][j], 0, 0, 0);
    __syncthreads();
  }
  dotbuf[arow][tid & 1] = dp;
  // scatter acc -> LDS transpose buffer (overlays staging; K-loop is done)
  {
    int q = lane >> 4, l16 = lane & 15;
    for (int i = 0; i < 4; ++i)
      for (int j = 0; j < 4; ++j) {
        int col = wc * 64 + j * 16 + l16;
        for (int rr = 0; rr < 4; ++rr) {
          int row = wr * 64 + i * 16 + q * 4 + rr;
          sm.C[row][col] = f2b(acc[i][j][rr]);
        }
      }
  }
  __syncthreads();
  if (tid < 128) {
    int r = r0 + tid;
    if (r < nrows) AOUT[r] = dotbuf[tid][0] + dotbuf[tid][1];
  }
  // vectorized store: each thread owns one row-half (64 cols = 8x dwordx4)
  {
    int r = tid >> 1, h = (tid & 1) * 64;
    int rg = r0 + r;
    if (rg < nrows) {
      uint4* po = (uint4*)(OUT + (size_t)rg * 128 + h);
      for (int k = 0; k < 8; ++k) {
        unsigned int a0 = *(const unsigned int*)&sm.C[r][h + k * 8];
        unsigned int a1 = *(const unsigned int*)&sm.C[r][h + k * 8 + 2];
        unsigned int a2 = *(const unsigned int*)&sm.C[r][h + k * 8 + 4];
        unsigned int a3 = *(const unsigned int*)&sm.C[r][h + k * 8 + 6];
        po[k] = make_uint4(a0, a1, a2, a3);
      }
    }
  }
}

// ---------------- edge stage: 64-edge tiles, A dbuf LDS, B frags from L2 (ping-pong) ----------------
// Round-4 body (best measured). Per K-chunk: {A reg->LDS(dbuf), 1-deep A+B
// prefetch, 1 barrier, 2 LDS A-frag reads, 8 MFMA}. B never touches LDS.
template <int KC0>
__global__ __launch_bounds__(256, 4)
void edge_fused(u16* HEF, const u16* ef, const u16* WeT, const u16* W_attn,
                const u16* b_edge, const u16* b_attn, const int* srcs, const int* dsts,
                const u16* Xs, const u16* Xd, const float* as_, const float* ad_,
                float* logit) {
  __shared__ union {
    __align__(16) u16 A[2][64][40];  // double-buffered A chunk (10.2KB)
    float C[64][65];                 // epilogue transpose (16.6KB); bank spread
  } sm;
  __shared__ float dotbuf[64];
  int blk = blockIdx.x, tid = threadIdx.x;
  int lane = tid & 63, wv = tid >> 6, wr = wv & 1, wc = wv >> 1;
  int q = lane >> 4, l16 = lane & 15;
  f32x4 acc[2][4];
  f32x4 zf = {0.f, 0.f, 0.f, 0.f};
  for (int i = 0; i < 2; ++i) for (int j = 0; j < 4; ++j) acc[i][j] = zf;
  float dp[2] = {0.f, 0.f};
  long e0 = (long)blk * 64;
  long ea = e0 + (tid >> 2);
  int qp = (tid & 3) * 8;  // A col offset (u16 units), 16B per thread
  const u16* wa = W_attn + 320;

  uint4 va = (KC0 < 4) ? *(const uint4*)(HEF + ea * 128 + KC0 * 32 + qp)
                       : *(const uint4*)(ef + ea * 32 + qp);
  bf16x8 bfp[2][4];
#pragma unroll
  for (int j = 0; j < 4; ++j)
    bfp[KC0 & 1][j] = *(const bf16x8*)(WeT + (size_t)(wc * 64 + j * 16 + l16) * 160 + KC0 * 32 + q * 8);

#pragma unroll
  for (int kc = KC0; kc < 5; ++kc) {
    int buf = kc & 1;
    *(uint4*)&sm.A[buf][tid >> 2][qp] = va;
    if (kc < 4) {  // issue next-chunk loads; latency hides under barrier+MFMA
      va = (kc + 1 < 4) ? *(const uint4*)(HEF + ea * 128 + (kc + 1) * 32 + qp)
                        : *(const uint4*)(ef + ea * 32 + qp);
#pragma unroll
      for (int j = 0; j < 4; ++j)
        bfp[(kc + 1) & 1][j] = *(const bf16x8*)(WeT + (size_t)(wc * 64 + j * 16 + l16) * 160 + (kc + 1) * 32 + q * 8);
    }
    __syncthreads();
    bf16x8 af[2];
    for (int i = 0; i < 2; ++i) af[i] = *(const bf16x8*)&sm.A[buf][wr * 32 + i * 16 + l16][q * 8];
    if (wc == 0) {
      bf16x8 wv8 = *(const bf16x8*)&wa[kc * 32 + q * 8];
      float wf[8];
      for (int j = 0; j < 8; ++j) wf[j] = b2f((u16)wv8[j]);
      for (int i = 0; i < 2; ++i)
        for (int j = 0; j < 8; ++j) dp[i] += b2f((u16)af[i][j]) * wf[j];
    }
    for (int i = 0; i < 2; ++i)
      for (int j = 0; j < 4; ++j)
        acc[i][j] = __builtin_amdgcn_mfma_f32_16x16x32_bf16(af[i], bfp[buf][j], acc[i][j], 0, 0, 0);
  }
  if (wc == 0) {
    for (int i = 0; i < 2; ++i) {
      dp[i] += __shfl_xor(dp[i], 16);
      dp[i] += __shfl_xor(dp[i], 32);
    }
    if (q == 0)
      for (int i = 0; i < 2; ++i) dotbuf[wr * 32 + i * 16 + l16] = dp[i];
  }
  int r = tid >> 2, qh = tid & 3;  // each thread: one edge row, 16 cols/pass
  long e = e0 + r;
  int s = srcs[e], d = dsts[e];
#pragma unroll
  for (int p = 0; p < 2; ++p) {
    int cb = p * 64 + qh * 16;
    // issue vector gathers early: latency hides under barrier + LDS scatter
    const uint4* ps = (const uint4*)(Xs + (size_t)s * 128 + cb);
    const uint4* pd = (const uint4*)(Xd + (size_t)d * 128 + cb);
    uint4 gs0 = ps[0], gs1 = ps[1], gd0 = pd[0], gd1 = pd[1];
    // p=0: wait for all waves' last A-reads + dotbuf writes before overlaying C
    // p=1: wait for pass-0 C reads before rewriting C
    __syncthreads();
    if (wc == p) {  // this wave pair's acc covers cols [p*64, p*64+64)
      for (int i = 0; i < 2; ++i)
        for (int j = 0; j < 4; ++j) {
          int col = j * 16 + l16;
          float bb = b2f(b_edge[p * 64 + col]);
          for (int rr = 0; rr < 4; ++rr)
            sm.C[wr * 32 + i * 16 + q * 4 + rr][col] = acc[i][j][rr] + bb;
        }
    }
    __syncthreads();
    if (p == 0 && tid < 64) {
      long ee = e0 + tid;
      logit[ee] = dotbuf[tid] + as_[srcs[ee]] + ad_[dsts[ee]] + b2f(b_attn[0]);
    }
    unsigned int us[8], ud[8];
    *(uint4*)&us[0] = gs0; *(uint4*)&us[4] = gs1;
    *(uint4*)&ud[0] = gd0; *(uint4*)&ud[4] = gd1;
    unsigned int ov[8];
    for (int w = 0; w < 8; ++w) {
      float c0 = sm.C[r][qh * 16 + 2 * w];
      float c1 = sm.C[r][qh * 16 + 2 * w + 1];
      float v0 = c0 + b2f((u16)(us[w] & 0xffffu)) + b2f((u16)(ud[w] & 0xffffu));
      float v1 = c1 + b2f((u16)(us[w] >> 16)) + b2f((u16)(ud[w] >> 16));
      ov[w] = (unsigned int)f2b(fmaxf(v0, 0.f)) | ((unsigned int)f2b(fmaxf(v1, 0.f)) << 16);
    }
    uint4* po = (uint4*)(HEF + e * 128 + cb);
    po[0] = *(uint4*)&ov[0];
    po[1] = *(uint4*)&ov[4];
  }
}

// ---------------- per-dst softmax + aggregation ----------------
// 1 wave per dst row; 8 edges/iteration with 2-deep software prefetch of the
// next group: lane = (edge-slot sub, col-group cl), 32B/lane M reads,
// 3-level shfl_xor fold over the 8 edge-slots.
__global__ __launch_bounds__(256)
void aggregate(const int* rowptr, const float* logit, const u16* M, u16* AGG, int nrows) {
  int gw = (blockIdx.x * blockDim.x + threadIdx.x) >> 6;
  int lane = threadIdx.x & 63;
  if (gw >= nrows) return;
  int beg = rowptr[gw], end = rowptr[gw + 1];
  int sub = lane >> 3, cl = lane & 7;
  float mx = -1e30f;
  for (int j = beg + lane; j < end; j += 64) mx = fmaxf(mx, logit[j]);
  for (int off = 32; off > 0; off >>= 1) mx = fmaxf(mx, __shfl_xor(mx, off));
  float acc[16];
  for (int t = 0; t < 16; ++t) acc[t] = 0.f;
  float denom = 0.f;
  // preload first group
  float wc = 0.f;
  uint4 m0c = make_uint4(0, 0, 0, 0), m1c = make_uint4(0, 0, 0, 0);
  {
    int j = beg + sub;
    if (j < end) {
      wc = __expf(logit[j] - mx);
      const uint4* mp = (const uint4*)(M + (size_t)j * 128 + cl * 16);
      m0c = mp[0]; m1c = mp[1];
    }
  }
  for (int j0 = beg; j0 < end; j0 += 8) {
    // issue next-group loads before consuming current (hides L2/L3 latency)
    float wn = 0.f;
    uint4 m0n = make_uint4(0, 0, 0, 0), m1n = make_uint4(0, 0, 0, 0);
    int jn = j0 + 8 + sub;
    if (jn < end) {
      wn = __expf(logit[jn] - mx);
      const uint4* mp = (const uint4*)(M + (size_t)jn * 128 + cl * 16);
      m0n = mp[0]; m1n = mp[1];
    }
    denom += wc;
    const unsigned int* mw0 = (const unsigned int*)&m0c;
    const unsigned int* mw1 = (const unsigned int*)&m1c;
    for (int t = 0; t < 4; ++t) {
      acc[2 * t]     += wc * b2f((u16)(mw0[t] & 0xffffu));
      acc[2 * t + 1] += wc * b2f((u16)(mw0[t] >> 16));
      acc[8 + 2 * t]     += wc * b2f((u16)(mw1[t] & 0xffffu));
      acc[8 + 2 * t + 1] += wc * b2f((u16)(mw1[t] >> 16));
    }
    wc = wn; m0c = m0n; m1c = m1n;
  }
  denom += __shfl_xor(denom, 8);
  denom += __shfl_xor(denom, 16);
  denom += __shfl_xor(denom, 32);
  for (int t = 0; t < 16; ++t) {
    acc[t] += __shfl_xor(acc[t], 8);
    acc[t] += __shfl_xor(acc[t], 16);
    acc[t] += __shfl_xor(acc[t], 32);
  }
  float inv = 1.0f / fmaxf(denom, 1e-16f);
  if (sub == 0) {
    unsigned int ov[8];
    for (int t = 0; t < 8; ++t)
      ov[t] = (unsigned int)f2b(acc[2 * t] * inv) | ((unsigned int)f2b(acc[2 * t + 1] * inv) << 16);
    uint4* po = (uint4*)(AGG + (size_t)gw * 128 + cl * 16);
    po[0] = *(uint4*)&ov[0];
    po[1] = *(uint4*)&ov[4];
  }
}

// ---------------- node update (MFMA, in-place HNF), 1-deep reg prefetch ----------------
__global__ __launch_bounds__(256)
void node_update(u16* HNF, const u16* nf, const u16* AGG, const u16* WnuT,
                 const u16* b_node, int kc0, int nrows) {
  __shared__ union {
    struct { __align__(16) u16 A[128][40]; __align__(16) u16 B[128][40]; } st;
    u16 C[128][130];
  } sm;
  int blk = blockIdx.x, tid = threadIdx.x;
  int lane = tid & 63, wv = tid >> 6, wr = wv & 1, wc = wv >> 1;
  f32x4 acc[4][4];
  f32x4 zf = {0.f, 0.f, 0.f, 0.f};
  for (int i = 0; i < 4; ++i) for (int j = 0; j < 4; ++j) acc[i][j] = zf;
  int arow = tid >> 1, ahalf = (tid & 1) * 16;
  int r0 = blk * 128;
  int ra = r0 + arow;
  auto asrc = [&](int kc) -> const u16* {
    if (kc < 4) return HNF + (size_t)ra * 128 + kc * 32 + ahalf;
    if (kc == 4) return nf + (size_t)ra * 32 + ahalf;
    return AGG + (size_t)ra * 128 + (kc - 5) * 32 + ahalf;
  };
  uint4 va0 = make_uint4(0, 0, 0, 0), va1 = make_uint4(0, 0, 0, 0), vb0, vb1;
  {
    if (ra < nrows) {
      const uint4* p = (const uint4*)asrc(kc0);
      va0 = p[0]; va1 = p[1];
    }
    const uint4* pb = (const uint4*)(WnuT + arow * 288 + kc0 * 32 + ahalf);
    vb0 = pb[0]; vb1 = pb[1];
  }
  for (int kc = kc0; kc < 9; ++kc) {
    *(uint4*)&sm.st.A[arow][ahalf] = va0;
    *(uint4*)&sm.st.A[arow][ahalf + 8] = va1;
    *(uint4*)&sm.st.B[arow][ahalf] = vb0;
    *(uint4*)&sm.st.B[arow][ahalf + 8] = vb1;
    if (kc < 8) {  // prefetch next chunk
      int kn = kc + 1;
      va0 = make_uint4(0, 0, 0, 0); va1 = make_uint4(0, 0, 0, 0);
      if (ra < nrows) {
        const uint4* p = (const uint4*)asrc(kn);
        va0 = p[0]; va1 = p[1];
      }
      const uint4* pb = (const uint4*)(WnuT + arow * 288 + kn * 32 + ahalf);
      vb0 = pb[0]; vb1 = pb[1];
    }
    __syncthreads();
    int q = lane >> 4, l16 = lane & 15;
    bf16x8 af[4], bfr[4];
    for (int i = 0; i < 4; ++i) af[i] = *(const bf16x8*)&sm.st.A[wr * 64 + i * 16 + l16][q * 8];
    for (int j = 0; j < 4; ++j) bfr[j] = *(const bf16x8*)&sm.st.B[wc * 64 + j * 16 + l16][q * 8];
    for (int i = 0; i < 4; ++i)
      for (int j = 0; j < 4; ++j)
        acc[i][j] = __builtin_amdgcn_mfma_f32_16x16x32_bf16(af[i], bfr[j], acc[i][j], 0, 0, 0);
    __syncthreads();
  }
  int q = lane >> 4, l16 = lane & 15;
  for (int i = 0; i < 4; ++i)
    for (int j = 0; j < 4; ++j) {
      int col = wc * 64 + j * 16 + l16;
      float bb = b2f(b_node[col]);
      for (int rr = 0; rr < 4; ++rr) {
        int row = wr * 64 + i * 16 + q * 4 + rr;
        sm.C[row][col] = f2b(fmaxf(acc[i][j][rr] + bb, 0.f));
      }
    }
  __syncthreads();
  {
    int r = tid >> 1, h = (tid & 1) * 64;
    int rg = r0 + r;
    if (rg < nrows) {
      uint4* po = (uint4*)(HNF + (size_t)rg * 128 + h);
      for (int k = 0; k < 8; ++k) {
        unsigned int a0 = *(const unsigned int*)&sm.C[r][h + k * 8];
        unsigned int a1 = *(const unsigned int*)&sm.C[r][h + k * 8 + 2];
        unsigned int a2 = *(const unsigned int*)&sm.C[r][h + k * 8 + 4];
        unsigned int a3 = *(const unsigned int*)&sm.C[r][h + k * 8 + 6];
        po[k] = make_uint4(a0, a1, a2, a3);
      }
    }
  }
}

// ---------------- output heads (MFMA, fp32 output, optional row remap) ----------------
// 1-deep reg prefetch of A (all threads) + B (wave 0) chunks.
__global__ __launch_bounds__(256)
void head_kernel(const u16* IN, const u16* WT, const u16* bias, float* OUT, long R,
                 const int* remap) {
  __shared__ __align__(16) u16 Asm[128][40];
  __shared__ __align__(16) u16 Bsm[32][40];
  int blk = blockIdx.x, tid = threadIdx.x;
  int lane = tid & 63, wv = tid >> 6;
  f32x4 acc[2][2];
  f32x4 zf = {0.f, 0.f, 0.f, 0.f};
  for (int i = 0; i < 2; ++i) for (int j = 0; j < 2; ++j) acc[i][j] = zf;
  int arow = tid >> 1, ahalf = (tid & 1) * 16;
  long r0 = (long)blk * 128;
  long ra = r0 + arow;
  uint4 va0 = make_uint4(0, 0, 0, 0), va1 = make_uint4(0, 0, 0, 0);
  uint4 vb0 = make_uint4(0, 0, 0, 0), vb1 = make_uint4(0, 0, 0, 0);
  {
    if (ra < R) {
      const uint4* p = (const uint4*)(IN + ra * 128 + 0 * 32 + ahalf);
      va0 = p[0]; va1 = p[1];
    }
    if (tid < 64) {
      const uint4* p = (const uint4*)(WT + arow * 128 + 0 * 32 + ahalf);
      vb0 = p[0]; vb1 = p[1];
    }
  }
  for (int kc = 0; kc < 4; ++kc) {
    *(uint4*)&Asm[arow][ahalf] = va0;
    *(uint4*)&Asm[arow][ahalf + 8] = va1;
    if (tid < 64) {
      *(uint4*)&Bsm[arow][ahalf] = vb0;
      *(uint4*)&Bsm[arow][ahalf + 8] = vb1;
    }
    if (kc < 3) {  // prefetch next chunk
      int kn = kc + 1;
      va0 = make_uint4(0, 0, 0, 0); va1 = make_uint4(0, 0, 0, 0);
      if (ra < R) {
        const uint4* p = (const uint4*)(IN + ra * 128 + kn * 32 + ahalf);
        va0 = p[0]; va1 = p[1];
      }
      if (tid < 64) {
        const uint4* p = (const uint4*)(WT + arow * 128 + kn * 32 + ahalf);
        vb0 = p[0]; vb1 = p[1];
      }
    }
    __syncthreads();
    int q = lane >> 4, l16 = lane & 15;
    bf16x8 af[2], bfr[2];
    for (int i = 0; i < 2; ++i) af[i] = *(const bf16x8*)&Asm[wv * 32 + i * 16 + l16][q * 8];
    for (int j = 0; j < 2; ++j) bfr[j] = *(const bf16x8*)&Bsm[j * 16 + l16][q * 8];
    for (int i = 0; i < 2; ++i)
      for (int j = 0; j < 2; ++j)
        acc[i][j] = __builtin_amdgcn_mfma_f32_16x16x32_bf16(af[i], bfr[j], acc[i][j], 0, 0, 0);
    __syncthreads();
  }
  int q = lane >> 4, l16 = lane & 15;
  for (int i = 0; i < 2; ++i)
    for (int rr = 0; rr < 4; ++rr) {
      long r = r0 + wv * 32 + i * 16 + q * 4 + rr;
      if (r < R) {
        long ro = remap ? (long)remap[r] : r;
        for (int j = 0; j < 2; ++j) {
          int col = j * 16 + l16;
          OUT[ro * 32 + col] = acc[i][j][rr] + b2f(bias[col]);
        }
      }
    }
}

extern "C" void kernel_launch(void* const* d_in, const int* in_sizes, int n_in,
                              void* d_out, int out_size, void* d_ws, size_t ws_size,
                              hipStream_t stream) {
  const size_t REQUIRED = 160000000;
  if (ws_size < REQUIRED) return;

  const void* nf_r = d_in[0];
  const void* ef_r = d_in[1];
  const int* src = (const int*)d_in[2];
  const int* dst = (const int*)d_in[3];

  char* ws = (char*)d_ws;
  auto alloc = [&](size_t bytes) {
    char* p = ws;
    ws += (bytes + 255) & ~(size_t)255;
    return p;
  };
  u16* HEF = (u16*)alloc((size_t)GE * 128 * 2);
  u16* HNF = (u16*)alloc((size_t)GN * 128 * 2);
  u16* Xs = (u16*)alloc((size_t)GN * 128 * 2);
  u16* Xd = (u16*)alloc((size_t)GN * 128 * 2);
  float* as_ = (float*)alloc((size_t)GN * 4);
  float* ad_ = (float*)alloc((size_t)GN * 4);
  float* logit = (float*)alloc((size_t)GE * 4);
  int* rowptr = (int*)alloc((size_t)(GN + 1) * 4);
  int* cursor = (int*)alloc((size_t)GN * 4);
  int* eid = (int*)alloc((size_t)GE * 4);
  int* srcs = (int*)alloc((size_t)GE * 4);
  int* dsts = (int*)alloc((size_t)GE * 4);
  u16* WeT = (u16*)alloc(128 * 160 * 2);
  u16* WnpT = (u16*)alloc(256 * 160 * 2);
  u16* WnuT = (u16*)alloc(128 * 288 * 2);
  u16* WoN = (u16*)alloc(32 * 128 * 2);
  u16* WoE = (u16*)alloc(32 * 128 * 2);
  u16* nfc = (u16*)alloc((size_t)GN * 32 * 2);
  u16* efc = (u16*)alloc((size_t)GE * 32 * 2);
  u16* bec = (u16*)alloc(128 * 2);
  u16* Wac = (u16*)alloc(480 * 2);
  u16* bac = (u16*)alloc(2);
  u16* bnc = (u16*)alloc(128 * 2);
  u16* bnoc = (u16*)alloc(32 * 2);
  u16* beoc = (u16*)alloc(32 * 2);
  int* dflag = (int*)alloc(4);
  u16* AGG = Xs;  // overlay: Xs (bf16, 6.4MB) dead after edge stage; AGG consumed
                  // by node_update before next iter's node_proj rewrites Xs

  detect_dtype<<<1, 64, 0, stream>>>(nf_r, dflag);
  // CSR build first (gathers depend on eid)
  hipMemsetAsync(cursor, 0, (size_t)GN * 4, stream);
  hist_kernel<<<1563, 256, 0, stream>>>(dst, cursor, GE);
  scan_kernel<<<1, 1024, 0, stream>>>(cursor, rowptr, GN);
  fill_kernel<<<1563, 256, 0, stream>>>(src, dst, cursor, eid, srcs, dsts, GE);

  convert_kernel<<<784, 256, 0, stream>>>(nf_r, nfc, (long)GN * 32, dflag);
  gather_ef<<<6250, 256, 0, stream>>>(ef_r, eid, efc, dflag);
  prep_weights<<<128, 256, 0, stream>>>(d_in[4], d_in[8], d_in[6], d_in[10], d_in[12],
                                        d_in[5], d_in[7], d_in[9], d_in[11], d_in[13],
                                        WeT, WnpT, WnuT, WoN, WoE,
                                        Wac, bec, bac, bnc, bnoc, beoc, dflag);

  for (int iter = 0; iter < 3; ++iter) {
    int kc0 = (iter == 0) ? 4 : 0;
    dim3 npgrid(NODE_BLKS, 2);
    node_proj<<<npgrid, 256, 0, stream>>>(HNF, nfc, WnpT, Wac, Xs, Xd, as_, ad_, kc0, GN);
    if (iter == 0)
      edge_fused<4><<<EDGE_BLKS, 256, 0, stream>>>(HEF, efc, WeT, Wac, bec, bac, srcs, dsts,
                                                   Xs, Xd, as_, ad_, logit);
    else
      edge_fused<0><<<EDGE_BLKS, 256, 0, stream>>>(HEF, efc, WeT, Wac, bec, bac, srcs, dsts,
                                                   Xs, Xd, as_, ad_, logit);
    aggregate<<<(GN + 3) / 4, 256, 0, stream>>>(rowptr, logit, HEF, AGG, GN);
    node_update<<<NODE_BLKS, 256, 0, stream>>>(HNF, nfc, AGG, WnuT, bnc, kc0, GN);
  }

  float* out_nf = (float*)d_out;
  float* out_ef = (float*)d_out + (size_t)GN * 32;
  head_kernel<<<NODE_BLKS, 256, 0, stream>>>(HNF, WoN, bnoc, out_nf, GN, nullptr);
  head_kernel<<<HEAD_EBLKS, 256, 0, stream>>>(HEF, WoE, beoc, out_ef, GE, eid);
}

// Round 7
// 593.543 us; speedup vs baseline: 1.1937x; 1.0170x over previous
//
#include <hip/hip_runtime.h>

// IJGNN attention-MPNN, 3 iterations. fp32 in/out, bf16 internal.
// Edges processed in dst-sorted (CSR) order; edge head scatters back via eid.
// This rev: output heads FUSED into the producers' epilogues --
//  - edge head: last edge_fused keeps M in an LDS bf16 tile (Mt[64][136]) and
//    runs the 128->32 MFMA head GEMM + eid-scattered out_ef writes in-kernel,
//    eliminating head_kernel's 102MB HEF re-read.
//  - node head: last node_update reuses its LDS C tile (final HNF bf16) for
//    the 128->32 head GEMM -> out_nf. head_kernel deleted entirely.
// Everything else = round-6 (edge_fused round-4 body @75us, prefetched node
// GEMMs, scan 1024, vectorized gather_ef, aggregate 8-edge prefetch).

#define GN 25000
#define GE 400000
#define NODE_BLKS 196    // ceil(GN/128)
#define EDGE_BLKS 6250   // GE/64 exact (edge_fused tiles)

typedef unsigned short u16;
typedef __attribute__((ext_vector_type(8))) short bf16x8;
typedef __attribute__((ext_vector_type(4))) float f32x4;

__device__ inline float b2f(u16 v) {
  union { unsigned int u; float f; } x; x.u = ((unsigned int)v) << 16; return x.f;
}
__device__ inline u16 f2b(float f) {
  union { float f; unsigned int u; } x; x.f = f;
  unsigned int u = x.u;
  u += 0x7fffu + ((u >> 16) & 1u);
  return (u16)(u >> 16);
}

// ---------------- dtype probe + convert ----------------
__global__ void detect_dtype(const void* nf, int* flag) {
  if (blockIdx.x == 0 && threadIdx.x == 0) {
    const u16* p = (const u16*)nf;
    int cnt = 0;
    for (int i = 0; i < 512; i += 2) {
      int e = (p[i] >> 7) & 0xFF;
      if (e >= 0x70 && e <= 0x85) cnt++;
    }
    *flag = (cnt < 128) ? 1 : 0;
  }
}

__global__ void convert_kernel(const void* src, u16* dst, long n, const int* flag) {
  int f32 = *flag;
  long i = (long)blockIdx.x * blockDim.x + threadIdx.x;
  long stride = (long)gridDim.x * blockDim.x;
  for (; i < n; i += stride)
    dst[i] = f32 ? f2b(((const float*)src)[i]) : ((const u16*)src)[i];
}

// gather ef rows into dst-sorted order (+convert), 16B per thread
__global__ void gather_ef(const void* ef, const int* eid, u16* efc, const int* flag) {
  int f32 = *flag;
  long idx = (long)blockIdx.x * blockDim.x + threadIdx.x;
  long ntot = (long)GE * 4;  // 8-col groups
  if (idx >= ntot) return;
  long j = idx >> 2;
  int g = (int)(idx & 3) * 8;
  long e = eid[j];
  uint4 out;
  if (f32) {
    const float* pf = (const float*)ef + e * 32 + g;
    float4 a = ((const float4*)pf)[0];
    float4 b = ((const float4*)pf)[1];
    unsigned int* ov = (unsigned int*)&out;
    ov[0] = (unsigned int)f2b(a.x) | ((unsigned int)f2b(a.y) << 16);
    ov[1] = (unsigned int)f2b(a.z) | ((unsigned int)f2b(a.w) << 16);
    ov[2] = (unsigned int)f2b(b.x) | ((unsigned int)f2b(b.y) << 16);
    ov[3] = (unsigned int)f2b(b.z) | ((unsigned int)f2b(b.w) << 16);
  } else {
    out = *(const uint4*)((const u16*)ef + e * 32 + g);
  }
  *(uint4*)(efc + j * 32 + g) = out;
}

// ---------------- weight prep: convert (raw f32/bf16) + transpose, one launch ----------------
__global__ void prep_weights(const void* We, const void* Wn, const void* Wa,
                             const void* Won, const void* Woe,
                             const void* be, const void* ba, const void* bn,
                             const void* bno, const void* beo,
                             u16* WeT, u16* WnpT, u16* WnuT, u16* WoN, u16* WoE,
                             u16* Wac, u16* bec, u16* bac, u16* bnc, u16* bnoc, u16* beoc,
                             const int* flag) {
  int f32 = *flag;
  auto ld = [&](const void* p, long i) -> u16 {
    return f32 ? f2b(((const float*)p)[i]) : ((const u16*)p)[i];
  };
  int tid = blockIdx.x * blockDim.x + threadIdx.x;
  int nt = gridDim.x * blockDim.x;
  for (int i = tid; i < 128 * 160; i += nt) { int n = i / 160, k = i % 160; WeT[i] = ld(We, (long)(320 + k) * 128 + n); }
  for (int i = tid; i < 256 * 160; i += nt) {
    int c = i / 160, k = i % 160;
    WnpT[i] = (c < 128) ? ld(We, (long)k * 128 + c) : ld(We, (long)(160 + k) * 128 + (c - 128));
  }
  for (int i = tid; i < 128 * 288; i += nt) { int c = i / 288, k = i % 288; WnuT[i] = ld(Wn, (long)k * 128 + c); }
  for (int i = tid; i < 32 * 128; i += nt) {
    int c = i / 128, k = i % 128;
    WoN[i] = ld(Won, (long)k * 32 + c);
    WoE[i] = ld(Woe, (long)k * 32 + c);
  }
  for (int i = tid; i < 480; i += nt) Wac[i] = ld(Wa, i);
  for (int i = tid; i < 128; i += nt) { bec[i] = ld(be, i); bnc[i] = ld(bn, i); }
  for (int i = tid; i < 32; i += nt) { bnoc[i] = ld(bno, i); beoc[i] = ld(beo, i); }
  if (tid == 0) bac[0] = ld(ba, 0);
}

// ---------------- CSR build ----------------
__global__ void hist_kernel(const int* dst, int* counts, int n) {
  for (int e = blockIdx.x * blockDim.x + threadIdx.x; e < n; e += gridDim.x * blockDim.x)
    atomicAdd(&counts[dst[e]], 1);
}

__global__ __launch_bounds__(1024) void scan_kernel(int* cursor, int* rowptr, int n) {
  __shared__ int part[1024];
  int t = threadIdx.x;
  int per = (n + 1023) / 1024;
  int lo = t * per;
  int hi = lo + per; if (hi > n) hi = n;
  if (lo > n) lo = n;
  int s = 0;
  for (int i = lo; i < hi; ++i) s += cursor[i];
  part[t] = s;
  __syncthreads();
  for (int off = 1; off < 1024; off <<= 1) {
    int v = (t >= off) ? part[t - off] : 0;
    __syncthreads();
    part[t] += v;
    __syncthreads();
  }
  int run = (t > 0) ? part[t - 1] : 0;
  for (int i = lo; i < hi; ++i) {
    int c = cursor[i];
    cursor[i] = run;
    rowptr[i + 1] = run + c;
    run += c;
  }
  if (t == 0) rowptr[0] = 0;
}

// fill CSR order + gather src/dst meta in the same pass
__global__ void fill_kernel(const int* src, const int* dst, int* cursor, int* eid,
                            int* srcs, int* dsts, int n) {
  for (int e = blockIdx.x * blockDim.x + threadIdx.x; e < n; e += gridDim.x * blockDim.x) {
    int d = dst[e];
    int p = atomicAdd(&cursor[d], 1);
    eid[p] = e;
    srcs[p] = src[e];
    dsts[p] = d;
  }
}

// ---------------- node projections (MFMA): Xs/Xd [N,128] bf16, as/ad [N] fp32 ----------------
// 1-deep reg prefetch: chunk kc+1 global loads issued after chunk kc's LDS
// write; latency hides under the dot + MFMA phase.
__global__ __launch_bounds__(256)
void node_proj(const u16* HNF, const u16* nf, const u16* WnpT, const u16* W_attn,
               u16* Xs, u16* Xd, float* as_, float* ad_, int kc0, int nrows) {
  __shared__ union {
    struct { __align__(16) u16 A[128][40]; __align__(16) u16 B[128][40]; } st;
    u16 C[128][130];  // bf16 transpose buffer (final values; no extra rounding)
  } sm;
  __shared__ float dotbuf[128][2];
  int sel = blockIdx.y, blk = blockIdx.x, tid = threadIdx.x;
  int lane = tid & 63, wv = tid >> 6, wr = wv & 1, wc = wv >> 1;
  const u16* BT = WnpT + sel * 128 * 160;
  u16* OUT = sel ? Xd : Xs;
  float* AOUT = sel ? ad_ : as_;
  const u16* wa = W_attn + sel * 160;
  f32x4 acc[4][4];
  f32x4 zf = {0.f, 0.f, 0.f, 0.f};
  for (int i = 0; i < 4; ++i) for (int j = 0; j < 4; ++j) acc[i][j] = zf;
  float dp = 0.f;
  int arow = tid >> 1, ahalf = (tid & 1) * 16;
  int r0 = blk * 128;
  int ra = r0 + arow;
  uint4 va0 = make_uint4(0, 0, 0, 0), va1 = make_uint4(0, 0, 0, 0), vb0, vb1;
  {
    if (ra < nrows) {
      const uint4* p = (kc0 < 4) ? (const uint4*)(HNF + (size_t)ra * 128 + kc0 * 32 + ahalf)
                                 : (const uint4*)(nf + (size_t)ra * 32 + ahalf);
      va0 = p[0]; va1 = p[1];
    }
    const uint4* pb = (const uint4*)(BT + arow * 160 + kc0 * 32 + ahalf);
    vb0 = pb[0]; vb1 = pb[1];
  }
  for (int kc = kc0; kc < 5; ++kc) {
    *(uint4*)&sm.st.A[arow][ahalf] = va0;
    *(uint4*)&sm.st.A[arow][ahalf + 8] = va1;
    *(uint4*)&sm.st.B[arow][ahalf] = vb0;
    *(uint4*)&sm.st.B[arow][ahalf + 8] = vb1;
    if (kc < 4) {  // prefetch next chunk
      int kn = kc + 1;
      va0 = make_uint4(0, 0, 0, 0); va1 = make_uint4(0, 0, 0, 0);
      if (ra < nrows) {
        const uint4* p = (kn < 4) ? (const uint4*)(HNF + (size_t)ra * 128 + kn * 32 + ahalf)
                                  : (const uint4*)(nf + (size_t)ra * 32 + ahalf);
        va0 = p[0]; va1 = p[1];
      }
      const uint4* pb = (const uint4*)(BT + arow * 160 + kn * 32 + ahalf);
      vb0 = pb[0]; vb1 = pb[1];
    }
    __syncthreads();
    {
      float s = 0.f;
      for (int j = 0; j < 16; ++j) s += b2f(sm.st.A[arow][ahalf + j]) * b2f(wa[kc * 32 + ahalf + j]);
      dp += s;
    }
    int q = lane >> 4, l16 = lane & 15;
    bf16x8 af[4], bfr[4];
    for (int i = 0; i < 4; ++i) af[i] = *(const bf16x8*)&sm.st.A[wr * 64 + i * 16 + l16][q * 8];
    for (int j = 0; j < 4; ++j) bfr[j] = *(const bf16x8*)&sm.st.B[wc * 64 + j * 16 + l16][q * 8];
    for (int i = 0; i < 4; ++i)
      for (int j = 0; j < 4; ++j)
        acc[i][j] = __builtin_amdgcn_mfma_f32_16x16x32_bf16(af[i], bfr[j], acc[i][j], 0, 0, 0);
    __syncthreads();
  }
  dotbuf[arow][tid & 1] = dp;
  // scatter acc -> LDS transpose buffer (overlays staging; K-loop is done)
  {
    int q = lane >> 4, l16 = lane & 15;
    for (int i = 0; i < 4; ++i)
      for (int j = 0; j < 4; ++j) {
        int col = wc * 64 + j * 16 + l16;
        for (int rr = 0; rr < 4; ++rr) {
          int row = wr * 64 + i * 16 + q * 4 + rr;
          sm.C[row][col] = f2b(acc[i][j][rr]);
        }
      }
  }
  __syncthreads();
  if (tid < 128) {
    int r = r0 + tid;
    if (r < nrows) AOUT[r] = dotbuf[tid][0] + dotbuf[tid][1];
  }
  // vectorized store: each thread owns one row-half (64 cols = 8x dwordx4)
  {
    int r = tid >> 1, h = (tid & 1) * 64;
    int rg = r0 + r;
    if (rg < nrows) {
      uint4* po = (uint4*)(OUT + (size_t)rg * 128 + h);
      for (int k = 0; k < 8; ++k) {
        unsigned int a0 = *(const unsigned int*)&sm.C[r][h + k * 8];
        unsigned int a1 = *(const unsigned int*)&sm.C[r][h + k * 8 + 2];
        unsigned int a2 = *(const unsigned int*)&sm.C[r][h + k * 8 + 4];
        unsigned int a3 = *(const unsigned int*)&sm.C[r][h + k * 8 + 6];
        po[k] = make_uint4(a0, a1, a2, a3);
      }
    }
  }
}

// ---------------- edge stage: 64-edge tiles, A dbuf LDS, B frags from L2 (ping-pong) ----------------
// Round-4 body. LAST=1 adds: M stashed to LDS Mt during epilogue, then a
// 64x128 @ 128x32 MFMA head GEMM (B = L2-hot WoE) + eid-scattered out_ef
// writes -- eliminates the separate head_kernel's 102MB HEF re-read.
template <int KC0, int LAST>
__global__ __launch_bounds__(256, 4)
void edge_fused(u16* HEF, const u16* ef, const u16* WeT, const u16* W_attn,
                const u16* b_edge, const u16* b_attn, const int* srcs, const int* dsts,
                const u16* Xs, const u16* Xd, const float* as_, const float* ad_,
                float* logit, const u16* WoE, const u16* b_eout, const int* eid,
                float* out_ef) {
  __shared__ union {
    __align__(16) u16 A[2][64][40];  // double-buffered A chunk (10.2KB)
    float C[64][65];                 // epilogue transpose (16.6KB); bank spread
  } sm;
  __shared__ float dotbuf[64];
  __shared__ __align__(16) u16 Mt[LAST ? 64 : 1][136];  // bf16 M tile for head GEMM
  int blk = blockIdx.x, tid = threadIdx.x;
  int lane = tid & 63, wv = tid >> 6, wr = wv & 1, wc = wv >> 1;
  int q = lane >> 4, l16 = lane & 15;
  f32x4 acc[2][4];
  f32x4 zf = {0.f, 0.f, 0.f, 0.f};
  for (int i = 0; i < 2; ++i) for (int j = 0; j < 4; ++j) acc[i][j] = zf;
  float dp[2] = {0.f, 0.f};
  long e0 = (long)blk * 64;
  long ea = e0 + (tid >> 2);
  int qp = (tid & 3) * 8;  // A col offset (u16 units), 16B per thread
  const u16* wa = W_attn + 320;

  uint4 va = (KC0 < 4) ? *(const uint4*)(HEF + ea * 128 + KC0 * 32 + qp)
                       : *(const uint4*)(ef + ea * 32 + qp);
  bf16x8 bfp[2][4];
#pragma unroll
  for (int j = 0; j < 4; ++j)
    bfp[KC0 & 1][j] = *(const bf16x8*)(WeT + (size_t)(wc * 64 + j * 16 + l16) * 160 + KC0 * 32 + q * 8);

#pragma unroll
  for (int kc = KC0; kc < 5; ++kc) {
    int buf = kc & 1;
    *(uint4*)&sm.A[buf][tid >> 2][qp] = va;
    if (kc < 4) {  // issue next-chunk loads; latency hides under barrier+MFMA
      va = (kc + 1 < 4) ? *(const uint4*)(HEF + ea * 128 + (kc + 1) * 32 + qp)
                        : *(const uint4*)(ef + ea * 32 + qp);
#pragma unroll
      for (int j = 0; j < 4; ++j)
        bfp[(kc + 1) & 1][j] = *(const bf16x8*)(WeT + (size_t)(wc * 64 + j * 16 + l16) * 160 + (kc + 1) * 32 + q * 8);
    }
    __syncthreads();
    bf16x8 af[2];
    for (int i = 0; i < 2; ++i) af[i] = *(const bf16x8*)&sm.A[buf][wr * 32 + i * 16 + l16][q * 8];
    if (wc == 0) {
      bf16x8 wv8 = *(const bf16x8*)&wa[kc * 32 + q * 8];
      float wf[8];
      for (int j = 0; j < 8; ++j) wf[j] = b2f((u16)wv8[j]);
      for (int i = 0; i < 2; ++i)
        for (int j = 0; j < 8; ++j) dp[i] += b2f((u16)af[i][j]) * wf[j];
    }
    for (int i = 0; i < 2; ++i)
      for (int j = 0; j < 4; ++j)
        acc[i][j] = __builtin_amdgcn_mfma_f32_16x16x32_bf16(af[i], bfp[buf][j], acc[i][j], 0, 0, 0);
  }
  if (wc == 0) {
    for (int i = 0; i < 2; ++i) {
      dp[i] += __shfl_xor(dp[i], 16);
      dp[i] += __shfl_xor(dp[i], 32);
    }
    if (q == 0)
      for (int i = 0; i < 2; ++i) dotbuf[wr * 32 + i * 16 + l16] = dp[i];
  }
  int r = tid >> 2, qh = tid & 3;  // each thread: one edge row, 16 cols/pass
  long e = e0 + r;
  int s = srcs[e], d = dsts[e];
#pragma unroll
  for (int p = 0; p < 2; ++p) {
    int cb = p * 64 + qh * 16;
    // issue vector gathers early: latency hides under barrier + LDS scatter
    const uint4* ps = (const uint4*)(Xs + (size_t)s * 128 + cb);
    const uint4* pd = (const uint4*)(Xd + (size_t)d * 128 + cb);
    uint4 gs0 = ps[0], gs1 = ps[1], gd0 = pd[0], gd1 = pd[1];
    // p=0: wait for all waves' last A-reads + dotbuf writes before overlaying C
    // p=1: wait for pass-0 C reads before rewriting C
    __syncthreads();
    if (wc == p) {  // this wave pair's acc covers cols [p*64, p*64+64)
      for (int i = 0; i < 2; ++i)
        for (int j = 0; j < 4; ++j) {
          int col = j * 16 + l16;
          float bb = b2f(b_edge[p * 64 + col]);
          for (int rr = 0; rr < 4; ++rr)
            sm.C[wr * 32 + i * 16 + q * 4 + rr][col] = acc[i][j][rr] + bb;
        }
    }
    __syncthreads();
    if (p == 0 && tid < 64) {
      long ee = e0 + tid;
      logit[ee] = dotbuf[tid] + as_[srcs[ee]] + ad_[dsts[ee]] + b2f(b_attn[0]);
    }
    unsigned int us[8], ud[8];
    *(uint4*)&us[0] = gs0; *(uint4*)&us[4] = gs1;
    *(uint4*)&ud[0] = gd0; *(uint4*)&ud[4] = gd1;
    unsigned int ov[8];
    for (int w = 0; w < 8; ++w) {
      float c0 = sm.C[r][qh * 16 + 2 * w];
      float c1 = sm.C[r][qh * 16 + 2 * w + 1];
      float v0 = c0 + b2f((u16)(us[w] & 0xffffu)) + b2f((u16)(ud[w] & 0xffffu));
      float v1 = c1 + b2f((u16)(us[w] >> 16)) + b2f((u16)(ud[w] >> 16));
      ov[w] = (unsigned int)f2b(fmaxf(v0, 0.f)) | ((unsigned int)f2b(fmaxf(v1, 0.f)) << 16);
    }
    if (LAST) {  // stash M for the fused head GEMM (same bf16 bits as HEF)
      *(uint4*)&Mt[r][cb] = *(uint4*)&ov[0];
      *(uint4*)&Mt[r][cb + 8] = *(uint4*)&ov[4];
    }
    uint4* po = (uint4*)(HEF + e * 128 + cb);
    po[0] = *(uint4*)&ov[0];
    po[1] = *(uint4*)&ov[4];
  }
  if (LAST) {
    __syncthreads();  // all Mt writes visible
    f32x4 ha0 = zf, ha1 = zf;  // wave wv: out rows [wv*16, wv*16+16), 32 cols
#pragma unroll
    for (int kc2 = 0; kc2 < 4; ++kc2) {
      bf16x8 af2 = *(const bf16x8*)&Mt[wv * 16 + l16][kc2 * 32 + q * 8];
      bf16x8 b0 = *(const bf16x8*)(WoE + (size_t)l16 * 128 + kc2 * 32 + q * 8);
      bf16x8 b1 = *(const bf16x8*)(WoE + (size_t)(16 + l16) * 128 + kc2 * 32 + q * 8);
      ha0 = __builtin_amdgcn_mfma_f32_16x16x32_bf16(af2, b0, ha0, 0, 0, 0);
      ha1 = __builtin_amdgcn_mfma_f32_16x16x32_bf16(af2, b1, ha1, 0, 0, 0);
    }
    float bb0 = b2f(b_eout[l16]), bb1 = b2f(b_eout[16 + l16]);
    for (int rr = 0; rr < 4; ++rr) {
      long ee = e0 + wv * 16 + q * 4 + rr;
      long ro = eid[ee];
      out_ef[ro * 32 + l16] = ha0[rr] + bb0;
      out_ef[ro * 32 + 16 + l16] = ha1[rr] + bb1;
    }
  }
}

// ---------------- per-dst softmax + aggregation ----------------
// 1 wave per dst row; 8 edges/iteration with 2-deep software prefetch of the
// next group: lane = (edge-slot sub, col-group cl), 32B/lane M reads,
// 3-level shfl_xor fold over the 8 edge-slots.
__global__ __launch_bounds__(256)
void aggregate(const int* rowptr, const float* logit, const u16* M, u16* AGG, int nrows) {
  int gw = (blockIdx.x * blockDim.x + threadIdx.x) >> 6;
  int lane = threadIdx.x & 63;
  if (gw >= nrows) return;
  int beg = rowptr[gw], end = rowptr[gw + 1];
  int sub = lane >> 3, cl = lane & 7;
  float mx = -1e30f;
  for (int j = beg + lane; j < end; j += 64) mx = fmaxf(mx, logit[j]);
  for (int off = 32; off > 0; off >>= 1) mx = fmaxf(mx, __shfl_xor(mx, off));
  float acc[16];
  for (int t = 0; t < 16; ++t) acc[t] = 0.f;
  float denom = 0.f;
  // preload first group
  float wc = 0.f;
  uint4 m0c = make_uint4(0, 0, 0, 0), m1c = make_uint4(0, 0, 0, 0);
  {
    int j = beg + sub;
    if (j < end) {
      wc = __expf(logit[j] - mx);
      const uint4* mp = (const uint4*)(M + (size_t)j * 128 + cl * 16);
      m0c = mp[0]; m1c = mp[1];
    }
  }
  for (int j0 = beg; j0 < end; j0 += 8) {
    // issue next-group loads before consuming current (hides L2/L3 latency)
    float wn = 0.f;
    uint4 m0n = make_uint4(0, 0, 0, 0), m1n = make_uint4(0, 0, 0, 0);
    int jn = j0 + 8 + sub;
    if (jn < end) {
      wn = __expf(logit[jn] - mx);
      const uint4* mp = (const uint4*)(M + (size_t)jn * 128 + cl * 16);
      m0n = mp[0]; m1n = mp[1];
    }
    denom += wc;
    const unsigned int* mw0 = (const unsigned int*)&m0c;
    const unsigned int* mw1 = (const unsigned int*)&m1c;
    for (int t = 0; t < 4; ++t) {
      acc[2 * t]     += wc * b2f((u16)(mw0[t] & 0xffffu));
      acc[2 * t + 1] += wc * b2f((u16)(mw0[t] >> 16));
      acc[8 + 2 * t]     += wc * b2f((u16)(mw1[t] & 0xffffu));
      acc[8 + 2 * t + 1] += wc * b2f((u16)(mw1[t] >> 16));
    }
    wc = wn; m0c = m0n; m1c = m1n;
  }
  denom += __shfl_xor(denom, 8);
  denom += __shfl_xor(denom, 16);
  denom += __shfl_xor(denom, 32);
  for (int t = 0; t < 16; ++t) {
    acc[t] += __shfl_xor(acc[t], 8);
    acc[t] += __shfl_xor(acc[t], 16);
    acc[t] += __shfl_xor(acc[t], 32);
  }
  float inv = 1.0f / fmaxf(denom, 1e-16f);
  if (sub == 0) {
    unsigned int ov[8];
    for (int t = 0; t < 8; ++t)
      ov[t] = (unsigned int)f2b(acc[2 * t] * inv) | ((unsigned int)f2b(acc[2 * t + 1] * inv) << 16);
    uint4* po = (uint4*)(AGG + (size_t)gw * 128 + cl * 16);
    po[0] = *(uint4*)&ov[0];
    po[1] = *(uint4*)&ov[4];
  }
}

// ---------------- node update (MFMA, in-place HNF), 1-deep reg prefetch ----------------
// LAST=1: node head fused -- final HNF bf16 already in LDS C; run the 128->32
// MFMA head GEMM (A-frags assembled from C via u32 reads, B = L2-hot WoN) and
// write out_nf directly. Bit-identical to the old separate head_kernel.
template <int LAST>
__global__ __launch_bounds__(256)
void node_update(u16* HNF, const u16* nf, const u16* AGG, const u16* WnuT,
                 const u16* b_node, int kc0, int nrows,
                 const u16* WoN, const u16* b_nout, float* out_nf) {
  __shared__ union {
    struct { __align__(16) u16 A[128][40]; __align__(16) u16 B[128][40]; } st;
    u16 C[128][130];
  } sm;
  int blk = blockIdx.x, tid = threadIdx.x;
  int lane = tid & 63, wv = tid >> 6, wr = wv & 1, wc = wv >> 1;
  f32x4 acc[4][4];
  f32x4 zf = {0.f, 0.f, 0.f, 0.f};
  for (int i = 0; i < 4; ++i) for (int j = 0; j < 4; ++j) acc[i][j] = zf;
  int arow = tid >> 1, ahalf = (tid & 1) * 16;
  int r0 = blk * 128;
  int ra = r0 + arow;
  auto asrc = [&](int kc) -> const u16* {
    if (kc < 4) return HNF + (size_t)ra * 128 + kc * 32 + ahalf;
    if (kc == 4) return nf + (size_t)ra * 32 + ahalf;
    return AGG + (size_t)ra * 128 + (kc - 5) * 32 + ahalf;
  };
  uint4 va0 = make_uint4(0, 0, 0, 0), va1 = make_uint4(0, 0, 0, 0), vb0, vb1;
  {
    if (ra < nrows) {
      const uint4* p = (const uint4*)asrc(kc0);
      va0 = p[0]; va1 = p[1];
    }
    const uint4* pb = (const uint4*)(WnuT + arow * 288 + kc0 * 32 + ahalf);
    vb0 = pb[0]; vb1 = pb[1];
  }
  for (int kc = kc0; kc < 9; ++kc) {
    *(uint4*)&sm.st.A[arow][ahalf] = va0;
    *(uint4*)&sm.st.A[arow][ahalf + 8] = va1;
    *(uint4*)&sm.st.B[arow][ahalf] = vb0;
    *(uint4*)&sm.st.B[arow][ahalf + 8] = vb1;
    if (kc < 8) {  // prefetch next chunk
      int kn = kc + 1;
      va0 = make_uint4(0, 0, 0, 0); va1 = make_uint4(0, 0, 0, 0);
      if (ra < nrows) {
        const uint4* p = (const uint4*)asrc(kn);
        va0 = p[0]; va1 = p[1];
      }
      const uint4* pb = (const uint4*)(WnuT + arow * 288 + kn * 32 + ahalf);
      vb0 = pb[0]; vb1 = pb[1];
    }
    __syncthreads();
    int q = lane >> 4, l16 = lane & 15;
    bf16x8 af[4], bfr[4];
    for (int i = 0; i < 4; ++i) af[i] = *(const bf16x8*)&sm.st.A[wr * 64 + i * 16 + l16][q * 8];
    for (int j = 0; j < 4; ++j) bfr[j] = *(const bf16x8*)&sm.st.B[wc * 64 + j * 16 + l16][q * 8];
    for (int i = 0; i < 4; ++i)
      for (int j = 0; j < 4; ++j)
        acc[i][j] = __builtin_amdgcn_mfma_f32_16x16x32_bf16(af[i], bfr[j], acc[i][j], 0, 0, 0);
    __syncthreads();
  }
  int q = lane >> 4, l16 = lane & 15;
  for (int i = 0; i < 4; ++i)
    for (int j = 0; j < 4; ++j) {
      int col = wc * 64 + j * 16 + l16;
      float bb = b2f(b_node[col]);
      for (int rr = 0; rr < 4; ++rr) {
        int row = wr * 64 + i * 16 + q * 4 + rr;
        sm.C[row][col] = f2b(fmaxf(acc[i][j][rr] + bb, 0.f));
      }
    }
  __syncthreads();
  {
    int r = tid >> 1, h = (tid & 1) * 64;
    int rg = r0 + r;
    if (rg < nrows) {
      uint4* po = (uint4*)(HNF + (size_t)rg * 128 + h);
      for (int k = 0; k < 8; ++k) {
        unsigned int a0 = *(const unsigned int*)&sm.C[r][h + k * 8];
        unsigned int a1 = *(const unsigned int*)&sm.C[r][h + k * 8 + 2];
        unsigned int a2 = *(const unsigned int*)&sm.C[r][h + k * 8 + 4];
        unsigned int a3 = *(const unsigned int*)&sm.C[r][h + k * 8 + 6];
        po[k] = make_uint4(a0, a1, a2, a3);
      }
    }
  }
  if (LAST) {  // fused node head: C holds final HNF bf16 (barrier above syncs)
    f32x4 ha[2][2];
    for (int i = 0; i < 2; ++i) for (int j = 0; j < 2; ++j) ha[i][j] = zf;
#pragma unroll
    for (int kc2 = 0; kc2 < 4; ++kc2) {
      bf16x8 af2[2], bf2[2];
      for (int i = 0; i < 2; ++i) {
        unsigned int* ap = (unsigned int*)&af2[i];
        int row = wv * 32 + i * 16 + l16;
        for (int w = 0; w < 4; ++w)
          ap[w] = *(const unsigned int*)&sm.C[row][kc2 * 32 + q * 8 + 2 * w];
      }
      for (int j = 0; j < 2; ++j)
        bf2[j] = *(const bf16x8*)(WoN + (size_t)(j * 16 + l16) * 128 + kc2 * 32 + q * 8);
      for (int i = 0; i < 2; ++i)
        for (int j = 0; j < 2; ++j)
          ha[i][j] = __builtin_amdgcn_mfma_f32_16x16x32_bf16(af2[i], bf2[j], ha[i][j], 0, 0, 0);
    }
    for (int i = 0; i < 2; ++i)
      for (int rr = 0; rr < 4; ++rr) {
        int rowg = r0 + wv * 32 + i * 16 + q * 4 + rr;
        if (rowg < nrows)
          for (int j = 0; j < 2; ++j)
            out_nf[(size_t)rowg * 32 + j * 16 + l16] = ha[i][j][rr] + b2f(b_nout[j * 16 + l16]);
      }
  }
}

extern "C" void kernel_launch(void* const* d_in, const int* in_sizes, int n_in,
                              void* d_out, int out_size, void* d_ws, size_t ws_size,
                              hipStream_t stream) {
  const size_t REQUIRED = 160000000;
  if (ws_size < REQUIRED) return;

  const void* nf_r = d_in[0];
  const void* ef_r = d_in[1];
  const int* src = (const int*)d_in[2];
  const int* dst = (const int*)d_in[3];

  char* ws = (char*)d_ws;
  auto alloc = [&](size_t bytes) {
    char* p = ws;
    ws += (bytes + 255) & ~(size_t)255;
    return p;
  };
  u16* HEF = (u16*)alloc((size_t)GE * 128 * 2);
  u16* HNF = (u16*)alloc((size_t)GN * 128 * 2);
  u16* Xs = (u16*)alloc((size_t)GN * 128 * 2);
  u16* Xd = (u16*)alloc((size_t)GN * 128 * 2);
  float* as_ = (float*)alloc((size_t)GN * 4);
  float* ad_ = (float*)alloc((size_t)GN * 4);
  float* logit = (float*)alloc((size_t)GE * 4);
  int* rowptr = (int*)alloc((size_t)(GN + 1) * 4);
  int* cursor = (int*)alloc((size_t)GN * 4);
  int* eid = (int*)alloc((size_t)GE * 4);
  int* srcs = (int*)alloc((size_t)GE * 4);
  int* dsts = (int*)alloc((size_t)GE * 4);
  u16* WeT = (u16*)alloc(128 * 160 * 2);
  u16* WnpT = (u16*)alloc(256 * 160 * 2);
  u16* WnuT = (u16*)alloc(128 * 288 * 2);
  u16* WoN = (u16*)alloc(32 * 128 * 2);
  u16* WoE = (u16*)alloc(32 * 128 * 2);
  u16* nfc = (u16*)alloc((size_t)GN * 32 * 2);
  u16* efc = (u16*)alloc((size_t)GE * 32 * 2);
  u16* bec = (u16*)alloc(128 * 2);
  u16* Wac = (u16*)alloc(480 * 2);
  u16* bac = (u16*)alloc(2);
  u16* bnc = (u16*)alloc(128 * 2);
  u16* bnoc = (u16*)alloc(32 * 2);
  u16* beoc = (u16*)alloc(32 * 2);
  int* dflag = (int*)alloc(4);
  u16* AGG = Xs;  // overlay: Xs (bf16, 6.4MB) dead after edge stage; AGG consumed
                  // by node_update before next iter's node_proj rewrites Xs

  float* out_nf = (float*)d_out;
  float* out_ef = (float*)d_out + (size_t)GN * 32;

  detect_dtype<<<1, 64, 0, stream>>>(nf_r, dflag);
  // CSR build first (gathers depend on eid)
  hipMemsetAsync(cursor, 0, (size_t)GN * 4, stream);
  hist_kernel<<<1563, 256, 0, stream>>>(dst, cursor, GE);
  scan_kernel<<<1, 1024, 0, stream>>>(cursor, rowptr, GN);
  fill_kernel<<<1563, 256, 0, stream>>>(src, dst, cursor, eid, srcs, dsts, GE);

  convert_kernel<<<784, 256, 0, stream>>>(nf_r, nfc, (long)GN * 32, dflag);
  gather_ef<<<6250, 256, 0, stream>>>(ef_r, eid, efc, dflag);
  prep_weights<<<128, 256, 0, stream>>>(d_in[4], d_in[8], d_in[6], d_in[10], d_in[12],
                                        d_in[5], d_in[7], d_in[9], d_in[11], d_in[13],
                                        WeT, WnpT, WnuT, WoN, WoE,
                                        Wac, bec, bac, bnc, bnoc, beoc, dflag);

  for (int iter = 0; iter < 3; ++iter) {
    int kc0 = (iter == 0) ? 4 : 0;
    dim3 npgrid(NODE_BLKS, 2);
    node_proj<<<npgrid, 256, 0, stream>>>(HNF, nfc, WnpT, Wac, Xs, Xd, as_, ad_, kc0, GN);
    if (iter == 0)
      edge_fused<4, 0><<<EDGE_BLKS, 256, 0, stream>>>(HEF, efc, WeT, Wac, bec, bac, srcs, dsts,
                                                      Xs, Xd, as_, ad_, logit, WoE, beoc, eid, out_ef);
    else if (iter == 1)
      edge_fused<0, 0><<<EDGE_BLKS, 256, 0, stream>>>(HEF, efc, WeT, Wac, bec, bac, srcs, dsts,
                                                      Xs, Xd, as_, ad_, logit, WoE, beoc, eid, out_ef);
    else
      edge_fused<0, 1><<<EDGE_BLKS, 256, 0, stream>>>(HEF, efc, WeT, Wac, bec, bac, srcs, dsts,
                                                      Xs, Xd, as_, ad_, logit, WoE, beoc, eid, out_ef);
    aggregate<<<(GN + 3) / 4, 256, 0, stream>>>(rowptr, logit, HEF, AGG, GN);
    if (iter < 2)
      node_update<0><<<NODE_BLKS, 256, 0, stream>>>(HNF, nfc, AGG, WnuT, bnc, kc0, GN,
                                                    WoN, bnoc, out_nf);
    else
      node_update<1><<<NODE_BLKS, 256, 0, stream>>>(HNF, nfc, AGG, WnuT, bnc, kc0, GN,
                                                    WoN, bnoc, out_nf);
  }
}